// Round 1
// baseline (4269.614 us; speedup 1.0000x reference)
//
#include <hip/hip_runtime.h>

#define NN 50000
#define NE 1600000
#define NG 16
#define HID 128
#define NEXP 4
#define LOGN_SCALE 9.210340371976184f

typedef unsigned short u16;
typedef unsigned int u32;
typedef __attribute__((ext_vector_type(8))) unsigned short ushort8;

static __device__ __forceinline__ float bf2f(u16 u){
  union { u32 i; float f; } c; c.i = ((u32)u)<<16; return c.f;
}
static __device__ __forceinline__ u16 f2bf(float f){
  union { float f; u32 i; } c; c.f = f;
  return (u16)((c.i + 0x7fffu + ((c.i>>16)&1u)) >> 16);
}

// ---- graph-size counts ----
__global__ void k_gcount(const int* __restrict__ batch, int* __restrict__ gcount){
  int t = blockIdx.x*blockDim.x + threadIdx.x;
  if(t < NN) atomicAdd(&gcount[batch[t]], 1);
}

// ---- per-node expert probs ----
__global__ void k_probs(const int* __restrict__ batch, const int* __restrict__ gcount,
                        const float* __restrict__ centers, float* __restrict__ probs){
  int n = blockIdx.x*blockDim.x + threadIdx.x;
  if(n >= NN) return;
  float c = (float)gcount[batch[n]];
  float logn = logf(fmaxf(c, 1.f)) * (1.f/LOGN_SCALE);
  float s[NEXP]; float m = -1e30f;
  #pragma unroll
  for(int e=0;e<NEXP;e++){ float d = logn - centers[e]; s[e] = -d*d; m = fmaxf(m, s[e]); }
  float sum = 0.f;
  #pragma unroll
  for(int e=0;e<NEXP;e++){ s[e] = expf(s[e]-m); sum += s[e]; }
  float inv = 1.f/sum;
  #pragma unroll
  for(int e=0;e<NEXP;e++) probs[n*NEXP+e] = s[e]*inv;
}

// ---- encoder: h0 = relu(x @ Wenc + benc), bf16 out ----
__global__ void k_enc(const float* __restrict__ x, const float* __restrict__ Wenc,
                      const float* __restrict__ benc, u16* __restrict__ h0){
  int t = blockIdx.x*blockDim.x + threadIdx.x;
  if(t >= NN*HID) return;
  int n = t >> 7, j = t & 127;
  float acc = benc[j];
  #pragma unroll
  for(int k=0;k<6;k++) acc += x[n*6+k]*Wenc[k*HID+j];
  h0[t] = f2bf(fmaxf(acc, 0.f));
}

// ---- convert conv weights to bf16: layout [e][l][{self,nbr}][128][128] ----
__global__ void k_wcvt(const float* __restrict__ Wself, const float* __restrict__ Wnbr,
                       u16* __restrict__ Wbf){
  int t = blockIdx.x*blockDim.x + threadIdx.x;
  if(t >= 12*HID*HID) return;
  int el = t / (HID*HID), i = t % (HID*HID);
  Wbf[(size_t)(el*2+0)*HID*HID + i] = f2bf(Wself[t]);
  Wbf[(size_t)(el*2+1)*HID*HID + i] = f2bf(Wnbr[t]);
}

// ---- CSR build ----
__global__ void k_deg(const int* __restrict__ dst, int* __restrict__ deg){
  int t = blockIdx.x*blockDim.x + threadIdx.x;
  if(t < NE) atomicAdd(&deg[dst[t]], 1);
}

__global__ __launch_bounds__(1024) void k_scan(const int* __restrict__ deg,
                                               int* __restrict__ offs, int* __restrict__ cursor){
  __shared__ int sd[1024];
  __shared__ int srun;
  if(threadIdx.x == 0) srun = 0;
  __syncthreads();
  for(int base=0; base<NN; base+=1024){
    int i = base + (int)threadIdx.x;
    int v = (i<NN) ? deg[i] : 0;
    sd[threadIdx.x] = v;
    __syncthreads();
    for(int d=1; d<1024; d<<=1){
      int t = (threadIdx.x>=(unsigned)d) ? sd[threadIdx.x-d] : 0;
      __syncthreads();
      sd[threadIdx.x] += t;
      __syncthreads();
    }
    int run = srun;
    if(i<NN){
      int excl = run + sd[threadIdx.x] - v;
      offs[i] = excl;
      cursor[i] = excl;
    }
    __syncthreads();
    if(threadIdx.x == 1023) srun = run + sd[1023];
    __syncthreads();
  }
  if(threadIdx.x == 0) offs[NN] = srun;
}

__global__ void k_fill(const int* __restrict__ src, const int* __restrict__ dst,
                       int* __restrict__ cursor, int* __restrict__ srcs){
  int t = blockIdx.x*blockDim.x + threadIdx.x;
  if(t >= NE) return;
  int p = atomicAdd(&cursor[dst[t]], 1);
  srcs[p] = src[t];
}

// ---- aggregation: one wave per node, VPL bf16 values per lane ----
template<int VPL>
__global__ __launch_bounds__(256) void k_agg(const u16* __restrict__ hin,
                                             const int* __restrict__ offs,
                                             const int* __restrict__ srcs,
                                             u16* __restrict__ hout){
  const int W = VPL*64;
  int node = blockIdx.x*4 + (threadIdx.x>>6);
  if(node >= NN) return;
  int lane = threadIdx.x & 63;
  float acc[VPL];
  #pragma unroll
  for(int i=0;i<VPL;i++) acc[i] = 0.f;
  int beg = offs[node], end = offs[node+1];
  for(int eb=beg; eb<end; eb+=64){
    int idx = eb + lane;
    int s = (idx < end) ? srcs[idx] : 0;
    int cnt = min(64, end-eb);
    for(int j=0;j<cnt;j++){
      int sj = __shfl(s, j, 64);
      const u16* p = hin + (size_t)sj*W + lane*VPL;
      if(VPL == 8){
        ushort8 v = *(const ushort8*)p;
        #pragma unroll
        for(int i=0;i<8;i++) acc[i] += bf2f(v[i]);
      } else {
        u32 v = *(const u32*)p;
        acc[0] += bf2f((u16)(v & 0xffffu));
        acc[1] += bf2f((u16)(v >> 16));
      }
    }
  }
  u16* o = hout + (size_t)node*W + lane*VPL;
  #pragma unroll
  for(int i=0;i<VPL;i++) o[i] = f2bf(acc[i]);
}

// ---- fused dual GEMM: hout[n][e][:] = act(hin@Ws + aggin@Wn + b) ----
#define NT_GEMM 64
template<bool RELU>
__global__ __launch_bounds__(256) void k_gemm(const u16* __restrict__ hin,
                                              const u16* __restrict__ aggin,
                                              int in_stride, int in_eoff,
                                              const u16* __restrict__ Wbf,
                                              const float* __restrict__ bconv,
                                              int layer,
                                              u16* __restrict__ hout){
  int e = blockIdx.y;
  const u16* Ws = Wbf + (size_t)((e*3+layer)*2)*HID*HID;
  const u16* Wn = Ws + HID*HID;
  const float* bias = bconv + (e*3+layer)*HID;
  __shared__ u16 WsL[HID*HID];
  __shared__ u16 WnL[HID*HID];
  {
    const uint4* s4 = (const uint4*)Ws;
    const uint4* n4 = (const uint4*)Wn;
    uint4* sl = (uint4*)WsL; uint4* nl = (uint4*)WnL;
    for(int i=threadIdx.x; i<HID*HID/8; i+=256){ sl[i]=s4[i]; nl[i]=n4[i]; }
  }
  __syncthreads();
  int wave = threadIdx.x >> 6, lane = threadIdx.x & 63;
  float b0 = bias[lane], b1 = bias[lane+64];
  int node0 = blockIdx.x*NT_GEMM;
  int nend = node0 + NT_GEMM; if(nend > NN) nend = NN;
  for(int nn = node0 + wave; nn < nend; nn += 4){
    const u16* hp = hin  + (size_t)nn*in_stride + e*in_eoff;
    const u16* ap = aggin + (size_t)nn*in_stride + e*in_eoff;
    float h_lo = bf2f(hp[lane]), h_hi = bf2f(hp[lane+64]);
    float a_lo = bf2f(ap[lane]), a_hi = bf2f(ap[lane+64]);
    float acc0 = b0, acc1 = b1;
    #pragma unroll 8
    for(int k=0;k<64;k++){
      float hk = __shfl(h_lo, k, 64);
      float ak = __shfl(a_lo, k, 64);
      acc0 += hk*bf2f(WsL[k*HID+lane])    + ak*bf2f(WnL[k*HID+lane]);
      acc1 += hk*bf2f(WsL[k*HID+lane+64]) + ak*bf2f(WnL[k*HID+lane+64]);
    }
    #pragma unroll 8
    for(int k=0;k<64;k++){
      float hk = __shfl(h_hi, k, 64);
      float ak = __shfl(a_hi, k, 64);
      acc0 += hk*bf2f(WsL[(k+64)*HID+lane])    + ak*bf2f(WnL[(k+64)*HID+lane]);
      acc1 += hk*bf2f(WsL[(k+64)*HID+lane+64]) + ak*bf2f(WnL[(k+64)*HID+lane+64]);
    }
    if(RELU){ acc0 = fmaxf(acc0, 0.f); acc1 = fmaxf(acc1, 0.f); }
    u16* op = hout + (size_t)nn*(NEXP*HID) + e*HID;
    op[lane] = f2bf(acc0); op[lane+64] = f2bf(acc1);
  }
}

// ---- final combine: out[n][j] = sum_e probs[n][e] * y[n][e][j] ----
__global__ void k_combine(const u16* __restrict__ y, const float* __restrict__ probs,
                          float* __restrict__ out){
  int t = blockIdx.x*blockDim.x + threadIdx.x;
  if(t >= NN*HID) return;
  int n = t >> 7, j = t & 127;
  const u16* yp = y + (size_t)n*(NEXP*HID);
  const float* pp = probs + n*NEXP;
  float r = pp[0]*bf2f(yp[j]) + pp[1]*bf2f(yp[HID+j])
          + pp[2]*bf2f(yp[2*HID+j]) + pp[3]*bf2f(yp[3*HID+j]);
  out[t] = r;
}

extern "C" void kernel_launch(void* const* d_in, const int* in_sizes, int n_in,
                              void* d_out, int out_size, void* d_ws, size_t ws_size,
                              hipStream_t stream){
  const float* x      = (const float*)d_in[0];
  const int*   eidx   = (const int*)d_in[1];
  const int*   batch  = (const int*)d_in[2];
  const float* Wenc   = (const float*)d_in[3];
  const float* benc   = (const float*)d_in[4];
  const float* Wself  = (const float*)d_in[5];
  const float* Wnbr   = (const float*)d_in[6];
  const float* bconv  = (const float*)d_in[7];
  const float* centers= (const float*)d_in[8];
  float* out = (float*)d_out;
  const int* src = eidx;
  const int* dst = eidx + NE;

  char* w = (char*)d_ws;
  size_t off = 0;
  auto alloc = [&](size_t b)->char*{ char* p = w + off; off = (off + b + 255) & ~(size_t)255; return p; };

  u16* h0    = (u16*)alloc((size_t)NN*HID*2);
  u16* agg0  = (u16*)alloc((size_t)NN*HID*2);
  u16* hA    = (u16*)alloc((size_t)NN*NEXP*HID*2);
  u16* hB    = (u16*)alloc((size_t)NN*NEXP*HID*2);
  u16* agg   = (u16*)alloc((size_t)NN*NEXP*HID*2);
  u16* Wbf   = (u16*)alloc((size_t)NEXP*3*2*HID*HID*2);
  float* probs = (float*)alloc((size_t)NN*NEXP*4);
  int* gcount = (int*)alloc(64);
  int* deg   = (int*)alloc((size_t)NN*4);
  int* offs  = (int*)alloc((size_t)(NN+1)*4);
  int* cursor= (int*)alloc((size_t)NN*4);
  int* srcs  = (int*)alloc((size_t)NE*4);
  if(off > ws_size) return;

  hipMemsetAsync(gcount, 0, 64, stream);
  hipMemsetAsync(deg, 0, (size_t)NN*4, stream);

  k_gcount<<<(NN+255)/256, 256, 0, stream>>>(batch, gcount);
  k_probs<<<(NN+255)/256, 256, 0, stream>>>(batch, gcount, centers, probs);
  k_enc<<<(NN*HID+255)/256, 256, 0, stream>>>(x, Wenc, benc, h0);
  k_wcvt<<<(12*HID*HID+255)/256, 256, 0, stream>>>(Wself, Wnbr, Wbf);
  k_deg<<<(NE+255)/256, 256, 0, stream>>>(dst, deg);
  k_scan<<<1, 1024, 0, stream>>>(deg, offs, cursor);
  k_fill<<<(NE+255)/256, 256, 0, stream>>>(src, dst, cursor, srcs);

  // layer 0: shared aggregation of h0, then per-expert dual GEMM
  k_agg<2><<<(NN+3)/4, 256, 0, stream>>>(h0, offs, srcs, agg0);
  k_gemm<true><<<dim3((NN+NT_GEMM-1)/NT_GEMM, NEXP), 256, 0, stream>>>(
      h0, agg0, HID, 0, Wbf, bconv, 0, hA);
  // layer 1
  k_agg<8><<<(NN+3)/4, 256, 0, stream>>>(hA, offs, srcs, agg);
  k_gemm<true><<<dim3((NN+NT_GEMM-1)/NT_GEMM, NEXP), 256, 0, stream>>>(
      hA, agg, NEXP*HID, HID, Wbf, bconv, 1, hB);
  // layer 2 (no relu)
  k_agg<8><<<(NN+3)/4, 256, 0, stream>>>(hB, offs, srcs, agg);
  k_gemm<false><<<dim3((NN+NT_GEMM-1)/NT_GEMM, NEXP), 256, 0, stream>>>(
      hB, agg, NEXP*HID, HID, Wbf, bconv, 2, hA);

  k_combine<<<(NN*HID+255)/256, 256, 0, stream>>>(hA, probs, out);
}

// Round 2
// 1639.849 us; speedup vs baseline: 2.6037x; 2.6037x over previous
//
#include <hip/hip_runtime.h>

#define NN 50000
#define NE 1600000
#define NG 16
#define HID 128
#define NEXP 4
#define LOGN_SCALE 9.210340371976184f

typedef unsigned short u16;
typedef unsigned int u32;
typedef __attribute__((ext_vector_type(8))) unsigned short ushort8;
typedef __attribute__((ext_vector_type(8))) short short8b;   // 8 bf16 = 4 VGPR
typedef __attribute__((ext_vector_type(4))) float f32x4;

static __device__ __forceinline__ float bf2f(u16 u){
  union { u32 i; float f; } c; c.i = ((u32)u)<<16; return c.f;
}
static __device__ __forceinline__ u16 f2bf(float f){
  union { float f; u32 i; } c; c.f = f;
  return (u16)((c.i + 0x7fffu + ((c.i>>16)&1u)) >> 16);
}

// ---- graph-size counts ----
__global__ void k_gcount(const int* __restrict__ batch, int* __restrict__ gcount){
  int t = blockIdx.x*blockDim.x + threadIdx.x;
  if(t < NN) atomicAdd(&gcount[batch[t]], 1);
}

// ---- per-node expert probs ----
__global__ void k_probs(const int* __restrict__ batch, const int* __restrict__ gcount,
                        const float* __restrict__ centers, float* __restrict__ probs){
  int n = blockIdx.x*blockDim.x + threadIdx.x;
  if(n >= NN) return;
  float c = (float)gcount[batch[n]];
  float logn = logf(fmaxf(c, 1.f)) * (1.f/LOGN_SCALE);
  float s[NEXP]; float m = -1e30f;
  #pragma unroll
  for(int e=0;e<NEXP;e++){ float d = logn - centers[e]; s[e] = -d*d; m = fmaxf(m, s[e]); }
  float sum = 0.f;
  #pragma unroll
  for(int e=0;e<NEXP;e++){ s[e] = expf(s[e]-m); sum += s[e]; }
  float inv = 1.f/sum;
  #pragma unroll
  for(int e=0;e<NEXP;e++) probs[n*NEXP+e] = s[e]*inv;
}

// ---- encoder: h0 = relu(x @ Wenc + benc), bf16 out ----
__global__ void k_enc(const float* __restrict__ x, const float* __restrict__ Wenc,
                      const float* __restrict__ benc, u16* __restrict__ h0){
  int t = blockIdx.x*blockDim.x + threadIdx.x;
  if(t >= NN*HID) return;
  int n = t >> 7, j = t & 127;
  float acc = benc[j];
  #pragma unroll
  for(int k=0;k<6;k++) acc += x[n*6+k]*Wenc[k*HID+j];
  h0[t] = f2bf(fmaxf(acc, 0.f));
}

// ---- weights -> bf16, transposed+concatenated: WbfT[(e*3+l)][col j][k 0..255]
//      k<128 -> Wself[k][j], k>=128 -> Wnbr[k-128][j]  (k contiguous) ----
__global__ void k_wcvtT(const float* __restrict__ Wself, const float* __restrict__ Wnbr,
                        u16* __restrict__ WbfT){
  int t = blockIdx.x*blockDim.x + threadIdx.x;
  if(t >= 12*HID*256) return;
  int el = t / (HID*256);
  int r  = t % (HID*256);
  int j  = r >> 8;
  int k  = r & 255;
  float v = (k < HID) ? Wself[(size_t)el*HID*HID + (size_t)k*HID + j]
                      : Wnbr [(size_t)el*HID*HID + (size_t)(k-HID)*HID + j];
  WbfT[t] = f2bf(v);
}

// ---- CSR build ----
__global__ void k_deg(const int* __restrict__ dst, int* __restrict__ deg){
  int t = blockIdx.x*blockDim.x + threadIdx.x;
  if(t < NE) atomicAdd(&deg[dst[t]], 1);
}

__global__ __launch_bounds__(1024) void k_scan(const int* __restrict__ deg,
                                               int* __restrict__ offs, int* __restrict__ cursor){
  __shared__ int sd[1024];
  __shared__ int srun;
  if(threadIdx.x == 0) srun = 0;
  __syncthreads();
  for(int base=0; base<NN; base+=1024){
    int i = base + (int)threadIdx.x;
    int v = (i<NN) ? deg[i] : 0;
    sd[threadIdx.x] = v;
    __syncthreads();
    for(int d=1; d<1024; d<<=1){
      int t = (threadIdx.x>=(unsigned)d) ? sd[threadIdx.x-d] : 0;
      __syncthreads();
      sd[threadIdx.x] += t;
      __syncthreads();
    }
    int run = srun;
    if(i<NN){
      int excl = run + sd[threadIdx.x] - v;
      offs[i] = excl;
      cursor[i] = excl;
    }
    __syncthreads();
    if(threadIdx.x == 1023) srun = run + sd[1023];
    __syncthreads();
  }
  if(threadIdx.x == 0) offs[NN] = srun;
}

__global__ void k_fill(const int* __restrict__ src, const int* __restrict__ dst,
                       int* __restrict__ cursor, int* __restrict__ srcs){
  int t = blockIdx.x*blockDim.x + threadIdx.x;
  if(t >= NE) return;
  int p = atomicAdd(&cursor[dst[t]], 1);
  srcs[p] = src[t];
}

// ---- aggregation: one wave per node, VPL bf16 values per lane ----
template<int VPL>
__global__ __launch_bounds__(256) void k_agg(const u16* __restrict__ hin,
                                             const int* __restrict__ offs,
                                             const int* __restrict__ srcs,
                                             u16* __restrict__ hout){
  const int W = VPL*64;
  int node = blockIdx.x*4 + (threadIdx.x>>6);
  if(node >= NN) return;
  int lane = threadIdx.x & 63;
  float acc[VPL];
  #pragma unroll
  for(int i=0;i<VPL;i++) acc[i] = 0.f;
  int beg = offs[node], end = offs[node+1];
  for(int eb=beg; eb<end; eb+=64){
    int idx = eb + lane;
    int s = (idx < end) ? srcs[idx] : 0;
    int cnt = min(64, end-eb);
    for(int j=0;j<cnt;j++){
      int sj = __shfl(s, j, 64);
      const u16* p = hin + (size_t)sj*W + lane*VPL;
      if(VPL == 8){
        ushort8 v = *(const ushort8*)p;
        #pragma unroll
        for(int i=0;i<8;i++) acc[i] += bf2f(v[i]);
      } else {
        u32 v = *(const u32*)p;
        acc[0] += bf2f((u16)(v & 0xffffu));
        acc[1] += bf2f((u16)(v >> 16));
      }
    }
  }
  u16* o = hout + (size_t)node*W + lane*VPL;
  #pragma unroll
  for(int i=0;i<VPL;i++) o[i] = f2bf(acc[i]);
}

// ---- MFMA dual GEMM: hout[n][e][:] = act([H|agg] @ [Ws;Wn] + b) ----
// K=256. B^T staged in registers (WbfT, k-contiguous). Wave = 32 rows x 32 cols.
#define RPB 256
template<bool RELU>
__global__ __launch_bounds__(256) void k_gemm_mfma(
    const u16* __restrict__ hin, const u16* __restrict__ aggin,
    int in_stride, int in_eoff,
    const u16* __restrict__ WbfT, const float* __restrict__ bconv,
    int layer, u16* __restrict__ hout)
{
  int e = blockIdx.y;
  int wave = threadIdx.x >> 6, lane = threadIdx.x & 63;
  int l16 = lane & 15, lq = lane >> 4;     // lq = k-quad (A/B) / row-quad (C)
  int c0 = wave*32;
  const u16* WT = WbfT + (size_t)((e*3+layer)*HID)*256;

  // B fragments, held for the whole kernel: Bf[ct][ks]
  short8b Bf[2][8];
  #pragma unroll
  for(int ct=0; ct<2; ct++){
    const u16* wp = WT + (size_t)(c0 + ct*16 + l16)*256 + lq*8;
    #pragma unroll
    for(int ks=0; ks<8; ks++)
      Bf[ct][ks] = *(const short8b*)(wp + ks*32);
  }
  const float* bias = bconv + (e*3+layer)*HID;
  float b0 = bias[c0 + l16], b1 = bias[c0 + 16 + l16];

  int nbase = blockIdx.x * RPB;
  #pragma unroll 1
  for(int it=0; it<RPB/32; it++){
    int n0 = nbase + it*32;
    if(n0 >= NN) break;
    f32x4 acc[2][2];
    #pragma unroll
    for(int rt=0; rt<2; rt++){
      acc[rt][0] = (f32x4){b0,b0,b0,b0};
      acc[rt][1] = (f32x4){b1,b1,b1,b1};
    }
    #pragma unroll
    for(int ks=0; ks<8; ks++){
      #pragma unroll
      for(int rt=0; rt<2; rt++){
        int n = n0 + rt*16 + l16;
        if(n > NN-1) n = NN-1;                       // clamp loads; writes guarded
        const u16* base = (ks < 4)
            ? (hin   + (size_t)n*in_stride + (size_t)e*in_eoff)
            : (aggin + (size_t)n*in_stride + (size_t)e*in_eoff - 128);
        short8b Af = *(const short8b*)(base + ks*32 + lq*8);
        acc[rt][0] = __builtin_amdgcn_mfma_f32_16x16x32_bf16(Af, Bf[0][ks], acc[rt][0], 0,0,0);
        acc[rt][1] = __builtin_amdgcn_mfma_f32_16x16x32_bf16(Af, Bf[1][ks], acc[rt][1], 0,0,0);
      }
    }
    // C/D layout: col = lane&15, row = (lane>>4)*4 + reg
    #pragma unroll
    for(int rt=0; rt<2; rt++){
      int rowb = n0 + rt*16 + lq*4;
      #pragma unroll
      for(int r=0; r<4; r++){
        int n = rowb + r;
        if(n < NN){
          float v0 = acc[rt][0][r], v1 = acc[rt][1][r];
          if(RELU){ v0 = fmaxf(v0, 0.f); v1 = fmaxf(v1, 0.f); }
          u16* op = hout + (size_t)n*(NEXP*HID) + e*HID;
          op[c0 + l16]      = f2bf(v0);
          op[c0 + 16 + l16] = f2bf(v1);
        }
      }
    }
  }
}

// ---- final combine: out[n][j] = sum_e probs[n][e] * y[n][e][j] ----
__global__ void k_combine(const u16* __restrict__ y, const float* __restrict__ probs,
                          float* __restrict__ out){
  int t = blockIdx.x*blockDim.x + threadIdx.x;
  if(t >= NN*HID) return;
  int n = t >> 7, j = t & 127;
  const u16* yp = y + (size_t)n*(NEXP*HID);
  const float* pp = probs + n*NEXP;
  float r = pp[0]*bf2f(yp[j]) + pp[1]*bf2f(yp[HID+j])
          + pp[2]*bf2f(yp[2*HID+j]) + pp[3]*bf2f(yp[3*HID+j]);
  out[t] = r;
}

extern "C" void kernel_launch(void* const* d_in, const int* in_sizes, int n_in,
                              void* d_out, int out_size, void* d_ws, size_t ws_size,
                              hipStream_t stream){
  const float* x      = (const float*)d_in[0];
  const int*   eidx   = (const int*)d_in[1];
  const int*   batch  = (const int*)d_in[2];
  const float* Wenc   = (const float*)d_in[3];
  const float* benc   = (const float*)d_in[4];
  const float* Wself  = (const float*)d_in[5];
  const float* Wnbr   = (const float*)d_in[6];
  const float* bconv  = (const float*)d_in[7];
  const float* centers= (const float*)d_in[8];
  float* out = (float*)d_out;
  const int* src = eidx;
  const int* dst = eidx + NE;

  char* w = (char*)d_ws;
  size_t off = 0;
  auto alloc = [&](size_t b)->char*{ char* p = w + off; off = (off + b + 255) & ~(size_t)255; return p; };

  u16* h0    = (u16*)alloc((size_t)NN*HID*2);
  u16* agg0  = (u16*)alloc((size_t)NN*HID*2);
  u16* hA    = (u16*)alloc((size_t)NN*NEXP*HID*2);
  u16* hB    = (u16*)alloc((size_t)NN*NEXP*HID*2);
  u16* agg   = (u16*)alloc((size_t)NN*NEXP*HID*2);
  u16* WbfT  = (u16*)alloc((size_t)12*HID*256*2);
  float* probs = (float*)alloc((size_t)NN*NEXP*4);
  int* gcount = (int*)alloc(64);
  int* deg   = (int*)alloc((size_t)NN*4);
  int* offs  = (int*)alloc((size_t)(NN+1)*4);
  int* cursor= (int*)alloc((size_t)NN*4);
  int* srcs  = (int*)alloc((size_t)NE*4);
  if(off > ws_size) return;

  hipMemsetAsync(gcount, 0, 64, stream);
  hipMemsetAsync(deg, 0, (size_t)NN*4, stream);

  k_gcount<<<(NN+255)/256, 256, 0, stream>>>(batch, gcount);
  k_probs<<<(NN+255)/256, 256, 0, stream>>>(batch, gcount, centers, probs);
  k_enc<<<(NN*HID+255)/256, 256, 0, stream>>>(x, Wenc, benc, h0);
  k_wcvtT<<<(12*HID*256+255)/256, 256, 0, stream>>>(Wself, Wnbr, WbfT);
  k_deg<<<(NE+255)/256, 256, 0, stream>>>(dst, deg);
  k_scan<<<1, 1024, 0, stream>>>(deg, offs, cursor);
  k_fill<<<(NE+255)/256, 256, 0, stream>>>(src, dst, cursor, srcs);

  dim3 ggrid((NN + RPB - 1)/RPB, NEXP);

  // layer 0: shared aggregation of h0, then per-expert dual MFMA GEMM
  k_agg<2><<<(NN+3)/4, 256, 0, stream>>>(h0, offs, srcs, agg0);
  k_gemm_mfma<true><<<ggrid, 256, 0, stream>>>(h0, agg0, HID, 0, WbfT, bconv, 0, hA);
  // layer 1
  k_agg<8><<<(NN+3)/4, 256, 0, stream>>>(hA, offs, srcs, agg);
  k_gemm_mfma<true><<<ggrid, 256, 0, stream>>>(hA, agg, NEXP*HID, HID, WbfT, bconv, 1, hB);
  // layer 2 (no relu)
  k_agg<8><<<(NN+3)/4, 256, 0, stream>>>(hB, offs, srcs, agg);
  k_gemm_mfma<false><<<ggrid, 256, 0, stream>>>(hB, agg, NEXP*HID, HID, WbfT, bconv, 2, hA);

  k_combine<<<(NN*HID+255)/256, 256, 0, stream>>>(hA, probs, out);
}

// Round 3
// 1073.925 us; speedup vs baseline: 3.9757x; 1.5270x over previous
//
#include <hip/hip_runtime.h>

#define NN 50000
#define NE 1600000
#define NG 16
#define HID 128
#define NEXP 4
#define LOGN_SCALE 9.210340371976184f

typedef unsigned short u16;
typedef unsigned int u32;
typedef __attribute__((ext_vector_type(8))) unsigned short ushort8;
typedef __attribute__((ext_vector_type(8))) short short8b;   // 8 bf16 = 4 VGPR
typedef __attribute__((ext_vector_type(4))) float f32x4;

static __device__ __forceinline__ float bf2f(u16 u){
  union { u32 i; float f; } c; c.i = ((u32)u)<<16; return c.f;
}
static __device__ __forceinline__ u16 f2bf(float f){
  union { float f; u32 i; } c; c.f = f;
  return (u16)((c.i + 0x7fffu + ((c.i>>16)&1u)) >> 16);
}

// ---- graph boundaries via binary search (batch is sorted) ----
__global__ void k_bounds(const int* __restrict__ batch, int* __restrict__ gstart){
  int g = threadIdx.x;
  if(g > NG) return;
  int lo = 0, hi = NN;
  while(lo < hi){ int mid = (lo+hi)>>1; if(batch[mid] < g) lo = mid+1; else hi = mid; }
  gstart[g] = lo;
}

// ---- per-node expert probs ----
__global__ void k_probs(const int* __restrict__ batch, const int* __restrict__ gstart,
                        const float* __restrict__ centers, float* __restrict__ probs){
  int n = blockIdx.x*blockDim.x + threadIdx.x;
  if(n >= NN) return;
  int b = batch[n];
  float c = (float)(gstart[b+1] - gstart[b]);
  float logn = logf(fmaxf(c, 1.f)) * (1.f/LOGN_SCALE);
  float s[NEXP]; float m = -1e30f;
  #pragma unroll
  for(int e=0;e<NEXP;e++){ float d = logn - centers[e]; s[e] = -d*d; m = fmaxf(m, s[e]); }
  float sum = 0.f;
  #pragma unroll
  for(int e=0;e<NEXP;e++){ s[e] = expf(s[e]-m); sum += s[e]; }
  float inv = 1.f/sum;
  #pragma unroll
  for(int e=0;e<NEXP;e++) probs[n*NEXP+e] = s[e]*inv;
}

// ---- encoder: h0 = relu(x @ Wenc + benc), bf16 out ----
__global__ void k_enc(const float* __restrict__ x, const float* __restrict__ Wenc,
                      const float* __restrict__ benc, u16* __restrict__ h0){
  int t = blockIdx.x*blockDim.x + threadIdx.x;
  if(t >= NN*HID) return;
  int n = t >> 7, j = t & 127;
  float acc = benc[j];
  #pragma unroll
  for(int k=0;k<6;k++) acc += x[n*6+k]*Wenc[k*HID+j];
  h0[t] = f2bf(fmaxf(acc, 0.f));
}

// ---- weights -> bf16, transposed+concatenated: WbfT[(e*3+l)][col j][k 0..255]
//      k<128 -> Wself[k][j], k>=128 -> Wnbr[k-128][j]  (k contiguous) ----
__global__ void k_wcvtT(const float* __restrict__ Wself, const float* __restrict__ Wnbr,
                        u16* __restrict__ WbfT){
  int t = blockIdx.x*blockDim.x + threadIdx.x;
  if(t >= 12*HID*256) return;
  int el = t / (HID*256);
  int r  = t % (HID*256);
  int j  = r >> 8;
  int k  = r & 255;
  float v = (k < HID) ? Wself[(size_t)el*HID*HID + (size_t)k*HID + j]
                      : Wnbr [(size_t)el*HID*HID + (size_t)(k-HID)*HID + j];
  WbfT[t] = f2bf(v);
}

// ---- CSR build ----
__global__ void k_deg(const int* __restrict__ dst, int* __restrict__ deg){
  int t = blockIdx.x*blockDim.x + threadIdx.x;
  if(t < NE) atomicAdd(&deg[dst[t]], 1);
}

__global__ __launch_bounds__(1024) void k_scan(const int* __restrict__ deg,
                                               int* __restrict__ offs, int* __restrict__ cursor){
  __shared__ int sd[1024];
  __shared__ int srun;
  if(threadIdx.x == 0) srun = 0;
  __syncthreads();
  for(int base=0; base<NN; base+=1024){
    int i = base + (int)threadIdx.x;
    int v = (i<NN) ? deg[i] : 0;
    sd[threadIdx.x] = v;
    __syncthreads();
    for(int d=1; d<1024; d<<=1){
      int t = (threadIdx.x>=(unsigned)d) ? sd[threadIdx.x-d] : 0;
      __syncthreads();
      sd[threadIdx.x] += t;
      __syncthreads();
    }
    int run = srun;
    if(i<NN){
      int excl = run + sd[threadIdx.x] - v;
      offs[i] = excl;
      cursor[i] = excl;
    }
    __syncthreads();
    if(threadIdx.x == 1023) srun = run + sd[1023];
    __syncthreads();
  }
  if(threadIdx.x == 0) offs[NN] = srun;
}

__global__ void k_fill(const int* __restrict__ src, const int* __restrict__ dst,
                       int* __restrict__ cursor, int* __restrict__ srcs){
  int t = blockIdx.x*blockDim.x + threadIdx.x;
  if(t >= NE) return;
  int p = atomicAdd(&cursor[dst[t]], 1);
  srcs[p] = src[t];
}

// ---- aggregation: one wave per node, VPL bf16 values per lane ----
template<int VPL>
__global__ __launch_bounds__(256) void k_agg(const u16* __restrict__ hin,
                                             const int* __restrict__ offs,
                                             const int* __restrict__ srcs,
                                             u16* __restrict__ hout){
  const int W = VPL*64;
  int node = blockIdx.x*4 + (threadIdx.x>>6);
  if(node >= NN) return;
  int lane = threadIdx.x & 63;
  float acc[VPL];
  #pragma unroll
  for(int i=0;i<VPL;i++) acc[i] = 0.f;
  int beg = offs[node], end = offs[node+1];
  for(int eb=beg; eb<end; eb+=64){
    int idx = eb + lane;
    int s = (idx < end) ? srcs[idx] : 0;
    int cnt = min(64, end-eb);
    for(int j=0;j<cnt;j++){
      int sj = __shfl(s, j, 64);
      const u16* p = hin + (size_t)sj*W + lane*VPL;
      if(VPL == 8){
        ushort8 v = *(const ushort8*)p;
        #pragma unroll
        for(int i=0;i<8;i++) acc[i] += bf2f(v[i]);
      } else {
        u32 v = *(const u32*)p;
        acc[0] += bf2f((u16)(v & 0xffffu));
        acc[1] += bf2f((u16)(v >> 16));
      }
    }
  }
  u16* o = hout + (size_t)node*W + lane*VPL;
  #pragma unroll
  for(int i=0;i<VPL;i++) o[i] = f2bf(acc[i]);
}

// ---- MFMA dual GEMM: hout[n][e][:] = act([H|agg] @ [Ws;Wn] + b) ----
// K=256. B^T staged in registers (WbfT, k-contiguous). Wave = 32 rows x 32 cols.
#define RPB 256
template<bool RELU>
__global__ __launch_bounds__(256) void k_gemm_mfma(
    const u16* __restrict__ hin, const u16* __restrict__ aggin,
    int in_stride, int in_eoff,
    const u16* __restrict__ WbfT, const float* __restrict__ bconv,
    int layer, u16* __restrict__ hout)
{
  int e = blockIdx.y;
  int wave = threadIdx.x >> 6, lane = threadIdx.x & 63;
  int l16 = lane & 15, lq = lane >> 4;     // lq = k-quad (A/B) / row-quad (C)
  int c0 = wave*32;
  const u16* WT = WbfT + (size_t)((e*3+layer)*HID)*256;

  // B fragments, held for the whole kernel: Bf[ct][ks]
  short8b Bf[2][8];
  #pragma unroll
  for(int ct=0; ct<2; ct++){
    const u16* wp = WT + (size_t)(c0 + ct*16 + l16)*256 + lq*8;
    #pragma unroll
    for(int ks=0; ks<8; ks++)
      Bf[ct][ks] = *(const short8b*)(wp + ks*32);
  }
  const float* bias = bconv + (e*3+layer)*HID;
  float b0 = bias[c0 + l16], b1 = bias[c0 + 16 + l16];

  int nbase = blockIdx.x * RPB;
  #pragma unroll 1
  for(int it=0; it<RPB/32; it++){
    int n0 = nbase + it*32;
    if(n0 >= NN) break;
    f32x4 acc[2][2];
    #pragma unroll
    for(int rt=0; rt<2; rt++){
      acc[rt][0] = (f32x4){b0,b0,b0,b0};
      acc[rt][1] = (f32x4){b1,b1,b1,b1};
    }
    #pragma unroll
    for(int ks=0; ks<8; ks++){
      #pragma unroll
      for(int rt=0; rt<2; rt++){
        int n = n0 + rt*16 + l16;
        if(n > NN-1) n = NN-1;                       // clamp loads; writes guarded
        const u16* base = (ks < 4)
            ? (hin   + (size_t)n*in_stride + (size_t)e*in_eoff)
            : (aggin + (size_t)n*in_stride + (size_t)e*in_eoff - 128);
        short8b Af = *(const short8b*)(base + ks*32 + lq*8);
        acc[rt][0] = __builtin_amdgcn_mfma_f32_16x16x32_bf16(Af, Bf[0][ks], acc[rt][0], 0,0,0);
        acc[rt][1] = __builtin_amdgcn_mfma_f32_16x16x32_bf16(Af, Bf[1][ks], acc[rt][1], 0,0,0);
      }
    }
    // C/D layout: col = lane&15, row = (lane>>4)*4 + reg
    #pragma unroll
    for(int rt=0; rt<2; rt++){
      int rowb = n0 + rt*16 + lq*4;
      #pragma unroll
      for(int r=0; r<4; r++){
        int n = rowb + r;
        if(n < NN){
          float v0 = acc[rt][0][r], v1 = acc[rt][1][r];
          if(RELU){ v0 = fmaxf(v0, 0.f); v1 = fmaxf(v1, 0.f); }
          u16* op = hout + (size_t)n*(NEXP*HID) + e*HID;
          op[c0 + l16]      = f2bf(v0);
          op[c0 + 16 + l16] = f2bf(v1);
        }
      }
    }
  }
}

// ---- final combine: out[n][j] = sum_e probs[n][e] * y[n][e][j] ----
__global__ void k_combine(const u16* __restrict__ y, const float* __restrict__ probs,
                          float* __restrict__ out){
  int t = blockIdx.x*blockDim.x + threadIdx.x;
  if(t >= NN*HID) return;
  int n = t >> 7, j = t & 127;
  const u16* yp = y + (size_t)n*(NEXP*HID);
  const float* pp = probs + n*NEXP;
  float r = pp[0]*bf2f(yp[j]) + pp[1]*bf2f(yp[HID+j])
          + pp[2]*bf2f(yp[2*HID+j]) + pp[3]*bf2f(yp[3*HID+j]);
  out[t] = r;
}

extern "C" void kernel_launch(void* const* d_in, const int* in_sizes, int n_in,
                              void* d_out, int out_size, void* d_ws, size_t ws_size,
                              hipStream_t stream){
  const float* x      = (const float*)d_in[0];
  const int*   eidx   = (const int*)d_in[1];
  const int*   batch  = (const int*)d_in[2];
  const float* Wenc   = (const float*)d_in[3];
  const float* benc   = (const float*)d_in[4];
  const float* Wself  = (const float*)d_in[5];
  const float* Wnbr   = (const float*)d_in[6];
  const float* bconv  = (const float*)d_in[7];
  const float* centers= (const float*)d_in[8];
  float* out = (float*)d_out;
  const int* src = eidx;
  const int* dst = eidx + NE;

  char* w = (char*)d_ws;
  size_t off = 0;
  auto alloc = [&](size_t b)->char*{ char* p = w + off; off = (off + b + 255) & ~(size_t)255; return p; };

  u16* h0    = (u16*)alloc((size_t)NN*HID*2);
  u16* agg0  = (u16*)alloc((size_t)NN*HID*2);
  u16* hA    = (u16*)alloc((size_t)NN*NEXP*HID*2);
  u16* hB    = (u16*)alloc((size_t)NN*NEXP*HID*2);
  u16* agg   = (u16*)alloc((size_t)NN*NEXP*HID*2);
  u16* WbfT  = (u16*)alloc((size_t)12*HID*256*2);
  float* probs = (float*)alloc((size_t)NN*NEXP*4);
  int* gstart = (int*)alloc(256);
  int* deg   = (int*)alloc((size_t)NN*4);
  int* offs  = (int*)alloc((size_t)(NN+1)*4);
  int* cursor= (int*)alloc((size_t)NN*4);
  int* srcs  = (int*)alloc((size_t)NE*4);
  if(off > ws_size) return;

  hipMemsetAsync(deg, 0, (size_t)NN*4, stream);

  k_bounds<<<1, 32, 0, stream>>>(batch, gstart);
  k_probs<<<(NN+255)/256, 256, 0, stream>>>(batch, gstart, centers, probs);
  k_enc<<<(NN*HID+255)/256, 256, 0, stream>>>(x, Wenc, benc, h0);
  k_wcvtT<<<(12*HID*256+255)/256, 256, 0, stream>>>(Wself, Wnbr, WbfT);
  k_deg<<<(NE+255)/256, 256, 0, stream>>>(dst, deg);
  k_scan<<<1, 1024, 0, stream>>>(deg, offs, cursor);
  k_fill<<<(NE+255)/256, 256, 0, stream>>>(src, dst, cursor, srcs);

  dim3 ggrid((NN + RPB - 1)/RPB, NEXP);

  // layer 0: shared aggregation of h0, then per-expert dual MFMA GEMM
  k_agg<2><<<(NN+3)/4, 256, 0, stream>>>(h0, offs, srcs, agg0);
  k_gemm_mfma<true><<<ggrid, 256, 0, stream>>>(h0, agg0, HID, 0, WbfT, bconv, 0, hA);
  // layer 1
  k_agg<8><<<(NN+3)/4, 256, 0, stream>>>(hA, offs, srcs, agg);
  k_gemm_mfma<true><<<ggrid, 256, 0, stream>>>(hA, agg, NEXP*HID, HID, WbfT, bconv, 1, hB);
  // layer 2 (no relu)
  k_agg<8><<<(NN+3)/4, 256, 0, stream>>>(hB, offs, srcs, agg);
  k_gemm_mfma<false><<<ggrid, 256, 0, stream>>>(hB, agg, NEXP*HID, HID, WbfT, bconv, 2, hA);

  k_combine<<<(NN*HID+255)/256, 256, 0, stream>>>(hA, probs, out);
}

// Round 4
// 952.230 us; speedup vs baseline: 4.4838x; 1.1278x over previous
//
#include <hip/hip_runtime.h>

#define NN 50000
#define NE 1600000
#define NG 16
#define HID 128
#define NEXP 4
#define LOGN_SCALE 9.210340371976184f
#define NB_SCAN 49   // ceil(NN/1024)

typedef unsigned short u16;
typedef unsigned int u32;
typedef __attribute__((ext_vector_type(8))) unsigned short ushort8;
typedef __attribute__((ext_vector_type(8))) short short8b;   // 8 bf16 = 4 VGPR
typedef __attribute__((ext_vector_type(4))) float f32x4;

static __device__ __forceinline__ float bf2f(u16 u){
  union { u32 i; float f; } c; c.i = ((u32)u)<<16; return c.f;
}
static __device__ __forceinline__ u16 f2bf(float f){
  union { float f; u32 i; } c; c.f = f;
  return (u16)((c.i + 0x7fffu + ((c.i>>16)&1u)) >> 16);
}

// ---- graph boundaries via binary search (batch is sorted) ----
__global__ void k_bounds(const int* __restrict__ batch, int* __restrict__ gstart){
  int g = threadIdx.x;
  if(g > NG) return;
  int lo = 0, hi = NN;
  while(lo < hi){ int mid = (lo+hi)>>1; if(batch[mid] < g) lo = mid+1; else hi = mid; }
  gstart[g] = lo;
}

// ---- per-node expert probs ----
__global__ void k_probs(const int* __restrict__ batch, const int* __restrict__ gstart,
                        const float* __restrict__ centers, float* __restrict__ probs){
  int n = blockIdx.x*blockDim.x + threadIdx.x;
  if(n >= NN) return;
  int b = batch[n];
  float c = (float)(gstart[b+1] - gstart[b]);
  float logn = logf(fmaxf(c, 1.f)) * (1.f/LOGN_SCALE);
  float s[NEXP]; float m = -1e30f;
  #pragma unroll
  for(int e=0;e<NEXP;e++){ float d = logn - centers[e]; s[e] = -d*d; m = fmaxf(m, s[e]); }
  float sum = 0.f;
  #pragma unroll
  for(int e=0;e<NEXP;e++){ s[e] = expf(s[e]-m); sum += s[e]; }
  float inv = 1.f/sum;
  #pragma unroll
  for(int e=0;e<NEXP;e++) probs[n*NEXP+e] = s[e]*inv;
}

// ---- encoder: h0 = relu(x @ Wenc + benc), bf16 out ----
__global__ void k_enc(const float* __restrict__ x, const float* __restrict__ Wenc,
                      const float* __restrict__ benc, u16* __restrict__ h0){
  int t = blockIdx.x*blockDim.x + threadIdx.x;
  if(t >= NN*HID) return;
  int n = t >> 7, j = t & 127;
  float acc = benc[j];
  #pragma unroll
  for(int k=0;k<6;k++) acc += x[n*6+k]*Wenc[k*HID+j];
  h0[t] = f2bf(fmaxf(acc, 0.f));
}

// ---- weights -> bf16, transposed+concatenated: WbfT[(e*3+l)][col j][k 0..255] ----
__global__ void k_wcvtT(const float* __restrict__ Wself, const float* __restrict__ Wnbr,
                        u16* __restrict__ WbfT){
  int t = blockIdx.x*blockDim.x + threadIdx.x;
  if(t >= 12*HID*256) return;
  int el = t / (HID*256);
  int r  = t % (HID*256);
  int j  = r >> 8;
  int k  = r & 255;
  float v = (k < HID) ? Wself[(size_t)el*HID*HID + (size_t)k*HID + j]
                      : Wnbr [(size_t)el*HID*HID + (size_t)(k-HID)*HID + j];
  WbfT[t] = f2bf(v);
}

// ---- CSR build ----
__global__ void k_deg(const int* __restrict__ dst, int* __restrict__ deg){
  int t = blockIdx.x*blockDim.x + threadIdx.x;
  if(t < NE) atomicAdd(&deg[dst[t]], 1);
}

// 3-phase scan: block-local scan + block sums, scan of sums, add-back
__global__ __launch_bounds__(1024) void k_scan1(const int* __restrict__ deg,
                                                int* __restrict__ offs, int* __restrict__ bsum){
  __shared__ int sd[1024];
  int i = blockIdx.x*1024 + threadIdx.x;
  int v = (i<NN) ? deg[i] : 0;
  sd[threadIdx.x] = v;
  __syncthreads();
  for(int d=1; d<1024; d<<=1){
    int t = (threadIdx.x>=(unsigned)d) ? sd[threadIdx.x-d] : 0;
    __syncthreads();
    sd[threadIdx.x] += t;
    __syncthreads();
  }
  if(i<NN) offs[i] = sd[threadIdx.x] - v;   // block-local exclusive
  if(threadIdx.x == 1023) bsum[blockIdx.x] = sd[1023];
}

__global__ void k_scan2(const int* __restrict__ bsum, int* __restrict__ boff){
  int lane = threadIdx.x;  // 64 threads
  int v = (lane < NB_SCAN) ? bsum[lane] : 0;
  int x = v;
  #pragma unroll
  for(int d=1; d<64; d<<=1){ int t = __shfl_up(x, d, 64); if(lane>=d) x += t; }
  if(lane < NB_SCAN) boff[lane] = x - v;
  if(lane == NB_SCAN-1) boff[NB_SCAN] = x;  // total
}

__global__ void k_scan3(int* __restrict__ offs, const int* __restrict__ boff,
                        int* __restrict__ cursor){
  int i = blockIdx.x*blockDim.x + threadIdx.x;
  if(i < NN){
    int o = offs[i] + boff[i>>10];
    offs[i] = o;
    cursor[i] = o;
  }
  if(i == 0) offs[NN] = boff[NB_SCAN];
}

__global__ void k_fill(const int* __restrict__ src, const int* __restrict__ dst,
                       int* __restrict__ cursor, int* __restrict__ srcs){
  int t = blockIdx.x*blockDim.x + threadIdx.x;
  if(t >= NE) return;
  int p = atomicAdd(&cursor[dst[t]], 1);
  srcs[p] = src[t];
}

// ---- aggregation: one wave per node, 8 edges' loads batched for MLP ----
template<int VPL>
__global__ __launch_bounds__(256) void k_agg(const u16* __restrict__ hin,
                                             const int* __restrict__ offs,
                                             const int* __restrict__ srcs,
                                             u16* __restrict__ hout){
  const int W = VPL*64;
  int node = blockIdx.x*4 + (threadIdx.x>>6);
  if(node >= NN) return;
  int lane = threadIdx.x & 63;
  const u16* hbase = hin + lane*VPL;
  float acc[VPL];
  #pragma unroll
  for(int i=0;i<VPL;i++) acc[i] = 0.f;
  int beg = offs[node], end = offs[node+1];
  for(int eb=beg; eb<end; eb+=64){
    int idx = eb + lane;
    int s = (idx < end) ? srcs[idx] : 0;
    int cnt = min(64, end-eb);
    int j = 0;
    if(VPL == 8){
      for(; j+8<=cnt; j+=8){
        ushort8 v[8];
        #pragma unroll
        for(int u=0;u<8;u++){
          int sj = __shfl(s, j+u, 64);
          v[u] = *(const ushort8*)(hbase + (size_t)sj*W);
        }
        #pragma unroll
        for(int u=0;u<8;u++){
          #pragma unroll
          for(int i=0;i<8;i++) acc[i] += bf2f((u16)v[u][i]);
        }
      }
      for(; j<cnt; j++){
        int sj = __shfl(s, j, 64);
        ushort8 v = *(const ushort8*)(hbase + (size_t)sj*W);
        #pragma unroll
        for(int i=0;i<8;i++) acc[i] += bf2f((u16)v[i]);
      }
    } else {
      for(; j+8<=cnt; j+=8){
        u32 v[8];
        #pragma unroll
        for(int u=0;u<8;u++){
          int sj = __shfl(s, j+u, 64);
          v[u] = *(const u32*)(hbase + (size_t)sj*W);
        }
        #pragma unroll
        for(int u=0;u<8;u++){
          acc[0] += bf2f((u16)(v[u] & 0xffffu));
          acc[1] += bf2f((u16)(v[u] >> 16));
        }
      }
      for(; j<cnt; j++){
        int sj = __shfl(s, j, 64);
        u32 v = *(const u32*)(hbase + (size_t)sj*W);
        acc[0] += bf2f((u16)(v & 0xffffu));
        acc[1] += bf2f((u16)(v >> 16));
      }
    }
  }
  u16* o = hout + (size_t)node*W + lane*VPL;
  #pragma unroll
  for(int i=0;i<VPL;i++) o[i] = f2bf(acc[i]);
}

// ---- MFMA dual GEMM: hout[n][e][:] = act([H|agg] @ [Ws;Wn] + b) ----
#define RPB 256
template<bool RELU>
__global__ __launch_bounds__(256) void k_gemm_mfma(
    const u16* __restrict__ hin, const u16* __restrict__ aggin,
    int in_stride, int in_eoff,
    const u16* __restrict__ WbfT, const float* __restrict__ bconv,
    int layer, u16* __restrict__ hout)
{
  int e = blockIdx.y;
  int wave = threadIdx.x >> 6, lane = threadIdx.x & 63;
  int l16 = lane & 15, lq = lane >> 4;
  int c0 = wave*32;
  const u16* WT = WbfT + (size_t)((e*3+layer)*HID)*256;

  short8b Bf[2][8];
  #pragma unroll
  for(int ct=0; ct<2; ct++){
    const u16* wp = WT + (size_t)(c0 + ct*16 + l16)*256 + lq*8;
    #pragma unroll
    for(int ks=0; ks<8; ks++)
      Bf[ct][ks] = *(const short8b*)(wp + ks*32);
  }
  const float* bias = bconv + (e*3+layer)*HID;
  float b0 = bias[c0 + l16], b1 = bias[c0 + 16 + l16];

  int nbase = blockIdx.x * RPB;
  #pragma unroll 1
  for(int it=0; it<RPB/32; it++){
    int n0 = nbase + it*32;
    if(n0 >= NN) break;
    f32x4 acc[2][2];
    #pragma unroll
    for(int rt=0; rt<2; rt++){
      acc[rt][0] = (f32x4){b0,b0,b0,b0};
      acc[rt][1] = (f32x4){b1,b1,b1,b1};
    }
    #pragma unroll
    for(int ks=0; ks<8; ks++){
      #pragma unroll
      for(int rt=0; rt<2; rt++){
        int n = n0 + rt*16 + l16;
        if(n > NN-1) n = NN-1;
        const u16* base = (ks < 4)
            ? (hin   + (size_t)n*in_stride + (size_t)e*in_eoff)
            : (aggin + (size_t)n*in_stride + (size_t)e*in_eoff - 128);
        short8b Af = *(const short8b*)(base + ks*32 + lq*8);
        acc[rt][0] = __builtin_amdgcn_mfma_f32_16x16x32_bf16(Af, Bf[0][ks], acc[rt][0], 0,0,0);
        acc[rt][1] = __builtin_amdgcn_mfma_f32_16x16x32_bf16(Af, Bf[1][ks], acc[rt][1], 0,0,0);
      }
    }
    #pragma unroll
    for(int rt=0; rt<2; rt++){
      int rowb = n0 + rt*16 + lq*4;
      #pragma unroll
      for(int r=0; r<4; r++){
        int n = rowb + r;
        if(n < NN){
          float v0 = acc[rt][0][r], v1 = acc[rt][1][r];
          if(RELU){ v0 = fmaxf(v0, 0.f); v1 = fmaxf(v1, 0.f); }
          u16* op = hout + (size_t)n*(NEXP*HID) + e*HID;
          op[c0 + l16]      = f2bf(v0);
          op[c0 + 16 + l16] = f2bf(v1);
        }
      }
    }
  }
}

// ---- final combine ----
__global__ void k_combine(const u16* __restrict__ y, const float* __restrict__ probs,
                          float* __restrict__ out){
  int t = blockIdx.x*blockDim.x + threadIdx.x;
  if(t >= NN*HID) return;
  int n = t >> 7, j = t & 127;
  const u16* yp = y + (size_t)n*(NEXP*HID);
  const float* pp = probs + n*NEXP;
  float r = pp[0]*bf2f(yp[j]) + pp[1]*bf2f(yp[HID+j])
          + pp[2]*bf2f(yp[2*HID+j]) + pp[3]*bf2f(yp[3*HID+j]);
  out[t] = r;
}

extern "C" void kernel_launch(void* const* d_in, const int* in_sizes, int n_in,
                              void* d_out, int out_size, void* d_ws, size_t ws_size,
                              hipStream_t stream){
  const float* x      = (const float*)d_in[0];
  const int*   eidx   = (const int*)d_in[1];
  const int*   batch  = (const int*)d_in[2];
  const float* Wenc   = (const float*)d_in[3];
  const float* benc   = (const float*)d_in[4];
  const float* Wself  = (const float*)d_in[5];
  const float* Wnbr   = (const float*)d_in[6];
  const float* bconv  = (const float*)d_in[7];
  const float* centers= (const float*)d_in[8];
  float* out = (float*)d_out;
  const int* src = eidx;
  const int* dst = eidx + NE;

  char* w = (char*)d_ws;
  size_t off = 0;
  auto alloc = [&](size_t b)->char*{ char* p = w + off; off = (off + b + 255) & ~(size_t)255; return p; };

  u16* h0    = (u16*)alloc((size_t)NN*HID*2);
  u16* agg0  = (u16*)alloc((size_t)NN*HID*2);
  u16* hA    = (u16*)alloc((size_t)NN*NEXP*HID*2);
  u16* hB    = (u16*)alloc((size_t)NN*NEXP*HID*2);
  u16* agg   = (u16*)alloc((size_t)NN*NEXP*HID*2);
  u16* WbfT  = (u16*)alloc((size_t)12*HID*256*2);
  float* probs = (float*)alloc((size_t)NN*NEXP*4);
  int* gstart = (int*)alloc(256);
  int* deg   = (int*)alloc((size_t)NN*4);
  int* offs  = (int*)alloc((size_t)(NN+1)*4);
  int* cursor= (int*)alloc((size_t)NN*4);
  int* srcs  = (int*)alloc((size_t)NE*4);
  int* bsum  = (int*)alloc((size_t)(NB_SCAN+1)*4);
  int* boff  = (int*)alloc((size_t)(NB_SCAN+1)*4);
  if(off > ws_size) return;

  hipMemsetAsync(deg, 0, (size_t)NN*4, stream);

  k_bounds<<<1, 32, 0, stream>>>(batch, gstart);
  k_probs<<<(NN+255)/256, 256, 0, stream>>>(batch, gstart, centers, probs);
  k_enc<<<(NN*HID+255)/256, 256, 0, stream>>>(x, Wenc, benc, h0);
  k_wcvtT<<<(12*HID*256+255)/256, 256, 0, stream>>>(Wself, Wnbr, WbfT);
  k_deg<<<(NE+255)/256, 256, 0, stream>>>(dst, deg);
  k_scan1<<<NB_SCAN, 1024, 0, stream>>>(deg, offs, bsum);
  k_scan2<<<1, 64, 0, stream>>>(bsum, boff);
  k_scan3<<<(NN+1023)/1024, 1024, 0, stream>>>(offs, boff, cursor);
  k_fill<<<(NE+255)/256, 256, 0, stream>>>(src, dst, cursor, srcs);

  dim3 ggrid((NN + RPB - 1)/RPB, NEXP);

  k_agg<2><<<(NN+3)/4, 256, 0, stream>>>(h0, offs, srcs, agg0);
  k_gemm_mfma<true><<<ggrid, 256, 0, stream>>>(h0, agg0, HID, 0, WbfT, bconv, 0, hA);
  k_agg<8><<<(NN+3)/4, 256, 0, stream>>>(hA, offs, srcs, agg);
  k_gemm_mfma<true><<<ggrid, 256, 0, stream>>>(hA, agg, NEXP*HID, HID, WbfT, bconv, 1, hB);
  k_agg<8><<<(NN+3)/4, 256, 0, stream>>>(hB, offs, srcs, agg);
  k_gemm_mfma<false><<<ggrid, 256, 0, stream>>>(hB, agg, NEXP*HID, HID, WbfT, bconv, 2, hA);

  k_combine<<<(NN*HID+255)/256, 256, 0, stream>>>(hA, probs, out);
}

// Round 5
// 714.947 us; speedup vs baseline: 5.9719x; 1.3319x over previous
//
#include <hip/hip_runtime.h>

#define NN 50000
#define NE 1600000
#define NG 16
#define HID 128
#define NEXP 4
#define LOGN_SCALE 9.210340371976184f
#define NB_SCAN 49   // ceil(NN/1024)

typedef unsigned short u16;
typedef unsigned int u32;
typedef unsigned char u8;
typedef __attribute__((ext_vector_type(8))) short short8b;   // 8 bf16 = 4 VGPR
typedef __attribute__((ext_vector_type(4))) float f32x4;
typedef __attribute__((ext_vector_type(2))) float f32x2;

static __device__ __forceinline__ float bf2f(u16 u){
  union { u32 i; float f; } c; c.i = ((u32)u)<<16; return c.f;
}
static __device__ __forceinline__ u16 f2bf(float f){
  union { float f; u32 i; } c; c.f = f;
  return (u16)((c.i + 0x7fffu + ((c.i>>16)&1u)) >> 16);
}
static __device__ __forceinline__ u8 f2fp8(float v){
  return (u8)(__builtin_amdgcn_cvt_pk_fp8_f32(v, v, 0, false) & 0xffu);
}

// ---- graph boundaries via binary search (batch is sorted) ----
__global__ void k_bounds(const int* __restrict__ batch, int* __restrict__ gstart){
  int g = threadIdx.x;
  if(g > NG) return;
  int lo = 0, hi = NN;
  while(lo < hi){ int mid = (lo+hi)>>1; if(batch[mid] < g) lo = mid+1; else hi = mid; }
  gstart[g] = lo;
}

// ---- per-node expert probs ----
__global__ void k_probs(const int* __restrict__ batch, const int* __restrict__ gstart,
                        const float* __restrict__ centers, float* __restrict__ probs){
  int n = blockIdx.x*blockDim.x + threadIdx.x;
  if(n >= NN) return;
  int b = batch[n];
  float c = (float)(gstart[b+1] - gstart[b]);
  float logn = logf(fmaxf(c, 1.f)) * (1.f/LOGN_SCALE);
  float s[NEXP]; float m = -1e30f;
  #pragma unroll
  for(int e=0;e<NEXP;e++){ float d = logn - centers[e]; s[e] = -d*d; m = fmaxf(m, s[e]); }
  float sum = 0.f;
  #pragma unroll
  for(int e=0;e<NEXP;e++){ s[e] = expf(s[e]-m); sum += s[e]; }
  float inv = 1.f/sum;
  #pragma unroll
  for(int e=0;e<NEXP;e++) probs[n*NEXP+e] = s[e]*inv;
}

// ---- encoder: h0 = relu(x @ Wenc + benc), bf16 + fp8 out ----
__global__ void k_enc(const float* __restrict__ x, const float* __restrict__ Wenc,
                      const float* __restrict__ benc, u16* __restrict__ h0,
                      u8* __restrict__ h08, float esc){
  int t = blockIdx.x*blockDim.x + threadIdx.x;
  if(t >= NN*HID) return;
  int n = t >> 7, j = t & 127;
  float acc = benc[j];
  #pragma unroll
  for(int k=0;k<6;k++) acc += x[n*6+k]*Wenc[k*HID+j];
  float v = fmaxf(acc, 0.f);
  h0[t] = f2bf(v);
  h08[t] = f2fp8(v*esc);
}

// ---- weights -> bf16, transposed+concatenated: WbfT[(e*3+l)][col j][k 0..255] ----
__global__ void k_wcvtT(const float* __restrict__ Wself, const float* __restrict__ Wnbr,
                        u16* __restrict__ WbfT){
  int t = blockIdx.x*blockDim.x + threadIdx.x;
  if(t >= 12*HID*256) return;
  int el = t / (HID*256);
  int r  = t % (HID*256);
  int j  = r >> 8;
  int k  = r & 255;
  float v = (k < HID) ? Wself[(size_t)el*HID*HID + (size_t)k*HID + j]
                      : Wnbr [(size_t)el*HID*HID + (size_t)(k-HID)*HID + j];
  WbfT[t] = f2bf(v);
}

// ---- CSR build ----
__global__ void k_deg(const int* __restrict__ dst, int* __restrict__ deg){
  int t = blockIdx.x*blockDim.x + threadIdx.x;
  if(t < NE) atomicAdd(&deg[dst[t]], 1);
}

__global__ __launch_bounds__(1024) void k_scan1(const int* __restrict__ deg,
                                                int* __restrict__ offs, int* __restrict__ bsum){
  __shared__ int sd[1024];
  int i = blockIdx.x*1024 + threadIdx.x;
  int v = (i<NN) ? deg[i] : 0;
  sd[threadIdx.x] = v;
  __syncthreads();
  for(int d=1; d<1024; d<<=1){
    int t = (threadIdx.x>=(unsigned)d) ? sd[threadIdx.x-d] : 0;
    __syncthreads();
    sd[threadIdx.x] += t;
    __syncthreads();
  }
  if(i<NN) offs[i] = sd[threadIdx.x] - v;
  if(threadIdx.x == 1023) bsum[blockIdx.x] = sd[1023];
}

__global__ void k_scan2(const int* __restrict__ bsum, int* __restrict__ boff){
  int lane = threadIdx.x;  // 64 threads
  int v = (lane < NB_SCAN) ? bsum[lane] : 0;
  int x = v;
  #pragma unroll
  for(int d=1; d<64; d<<=1){ int t = __shfl_up(x, d, 64); if(lane>=d) x += t; }
  if(lane < NB_SCAN) boff[lane] = x - v;
  if(lane == NB_SCAN-1) boff[NB_SCAN] = x;
}

__global__ void k_scan3(int* __restrict__ offs, const int* __restrict__ boff,
                        int* __restrict__ cursor){
  int i = blockIdx.x*blockDim.x + threadIdx.x;
  if(i < NN){
    int o = offs[i] + boff[i>>10];
    offs[i] = o;
    cursor[i] = o;
  }
  if(i == 0) offs[NN] = boff[NB_SCAN];
}

__global__ void k_fill(const int* __restrict__ src, const int* __restrict__ dst,
                       int* __restrict__ cursor, int* __restrict__ srcs){
  int t = blockIdx.x*blockDim.x + threadIdx.x;
  if(t >= NE) return;
  int p = atomicAdd(&cursor[dst[t]], 1);
  srcs[p] = src[t];
}

// ---- aggregation over fp8 table: one wave per node, BPL bytes per lane ----
template<int BPL>
__global__ __launch_bounds__(256) void k_agg8(const u8* __restrict__ hin,
                                              const int* __restrict__ offs,
                                              const int* __restrict__ srcs,
                                              u16* __restrict__ hout, float inv_scale){
  const int W = BPL*64;   // row bytes == row values
  int node = blockIdx.x*4 + (threadIdx.x>>6);
  if(node >= NN) return;
  int lane = threadIdx.x & 63;
  const u8* hbase = hin + lane*BPL;
  float acc[BPL];
  #pragma unroll
  for(int i=0;i<BPL;i++) acc[i] = 0.f;
  int beg = offs[node], end = offs[node+1];
  for(int eb=beg; eb<end; eb+=64){
    int idx = eb + lane;
    int s = (idx < end) ? srcs[idx] : 0;
    int cnt = min(64, end-eb);
    int j = 0;
    if(BPL == 8){
      for(; j+8<=cnt; j+=8){
        uint2 v[8];
        #pragma unroll
        for(int u=0;u<8;u++){
          int sj = __shfl(s, j+u, 64);
          v[u] = *(const uint2*)(hbase + (size_t)sj*W);
        }
        #pragma unroll
        for(int u=0;u<8;u++){
          f32x2 f0 = __builtin_amdgcn_cvt_pk_f32_fp8(v[u].x, false);
          f32x2 f1 = __builtin_amdgcn_cvt_pk_f32_fp8(v[u].x, true);
          f32x2 f2 = __builtin_amdgcn_cvt_pk_f32_fp8(v[u].y, false);
          f32x2 f3 = __builtin_amdgcn_cvt_pk_f32_fp8(v[u].y, true);
          acc[0]+=f0.x; acc[1]+=f0.y; acc[2]+=f1.x; acc[3]+=f1.y;
          acc[4]+=f2.x; acc[5]+=f2.y; acc[6]+=f3.x; acc[7]+=f3.y;
        }
      }
      for(; j<cnt; j++){
        int sj = __shfl(s, j, 64);
        uint2 v = *(const uint2*)(hbase + (size_t)sj*W);
        f32x2 f0 = __builtin_amdgcn_cvt_pk_f32_fp8(v.x, false);
        f32x2 f1 = __builtin_amdgcn_cvt_pk_f32_fp8(v.x, true);
        f32x2 f2 = __builtin_amdgcn_cvt_pk_f32_fp8(v.y, false);
        f32x2 f3 = __builtin_amdgcn_cvt_pk_f32_fp8(v.y, true);
        acc[0]+=f0.x; acc[1]+=f0.y; acc[2]+=f1.x; acc[3]+=f1.y;
        acc[4]+=f2.x; acc[5]+=f2.y; acc[6]+=f3.x; acc[7]+=f3.y;
      }
    } else {
      for(; j+8<=cnt; j+=8){
        u32 v[8];
        #pragma unroll
        for(int u=0;u<8;u++){
          int sj = __shfl(s, j+u, 64);
          v[u] = *(const u16*)(hbase + (size_t)sj*W);
        }
        #pragma unroll
        for(int u=0;u<8;u++){
          f32x2 f0 = __builtin_amdgcn_cvt_pk_f32_fp8(v[u], false);
          acc[0]+=f0.x; acc[1]+=f0.y;
        }
      }
      for(; j<cnt; j++){
        int sj = __shfl(s, j, 64);
        u32 v = *(const u16*)(hbase + (size_t)sj*W);
        f32x2 f0 = __builtin_amdgcn_cvt_pk_f32_fp8(v, false);
        acc[0]+=f0.x; acc[1]+=f0.y;
      }
    }
  }
  u16* o = hout + (size_t)node*W + lane*BPL;
  #pragma unroll
  for(int i=0;i<BPL;i++) o[i] = f2bf(acc[i]*inv_scale);
}

// ---- MFMA dual GEMM: hout[n][e][:] = act([H|agg] @ [Ws;Wn] + b), bf16 + fp8 out ----
#define RPB 256
template<bool RELU>
__global__ __launch_bounds__(256) void k_gemm_mfma(
    const u16* __restrict__ hin, const u16* __restrict__ aggin,
    int in_stride, int in_eoff,
    const u16* __restrict__ WbfT, const float* __restrict__ bconv,
    int layer, u16* __restrict__ hout, u8* __restrict__ hout8, float enc8)
{
  int e = blockIdx.y;
  int wave = threadIdx.x >> 6, lane = threadIdx.x & 63;
  int l16 = lane & 15, lq = lane >> 4;
  int c0 = wave*32;
  const u16* WT = WbfT + (size_t)((e*3+layer)*HID)*256;

  short8b Bf[2][8];
  #pragma unroll
  for(int ct=0; ct<2; ct++){
    const u16* wp = WT + (size_t)(c0 + ct*16 + l16)*256 + lq*8;
    #pragma unroll
    for(int ks=0; ks<8; ks++)
      Bf[ct][ks] = *(const short8b*)(wp + ks*32);
  }
  const float* bias = bconv + (e*3+layer)*HID;
  float b0 = bias[c0 + l16], b1 = bias[c0 + 16 + l16];

  int nbase = blockIdx.x * RPB;
  #pragma unroll 1
  for(int it=0; it<RPB/32; it++){
    int n0 = nbase + it*32;
    if(n0 >= NN) break;
    f32x4 acc[2][2];
    #pragma unroll
    for(int rt=0; rt<2; rt++){
      acc[rt][0] = (f32x4){b0,b0,b0,b0};
      acc[rt][1] = (f32x4){b1,b1,b1,b1};
    }
    #pragma unroll
    for(int ks=0; ks<8; ks++){
      #pragma unroll
      for(int rt=0; rt<2; rt++){
        int n = n0 + rt*16 + l16;
        if(n > NN-1) n = NN-1;
        const u16* base = (ks < 4)
            ? (hin   + (size_t)n*in_stride + (size_t)e*in_eoff)
            : (aggin + (size_t)n*in_stride + (size_t)e*in_eoff - 128);
        short8b Af = *(const short8b*)(base + ks*32 + lq*8);
        acc[rt][0] = __builtin_amdgcn_mfma_f32_16x16x32_bf16(Af, Bf[0][ks], acc[rt][0], 0,0,0);
        acc[rt][1] = __builtin_amdgcn_mfma_f32_16x16x32_bf16(Af, Bf[1][ks], acc[rt][1], 0,0,0);
      }
    }
    #pragma unroll
    for(int rt=0; rt<2; rt++){
      int rowb = n0 + rt*16 + lq*4;
      #pragma unroll
      for(int r=0; r<4; r++){
        int n = rowb + r;
        if(n < NN){
          float v0 = acc[rt][0][r], v1 = acc[rt][1][r];
          if(RELU){ v0 = fmaxf(v0, 0.f); v1 = fmaxf(v1, 0.f); }
          u16* op = hout + (size_t)n*(NEXP*HID) + e*HID;
          op[c0 + l16]      = f2bf(v0);
          op[c0 + 16 + l16] = f2bf(v1);
          if(hout8){
            u8* op8 = hout8 + (size_t)n*(NEXP*HID) + e*HID;
            op8[c0 + l16]      = f2fp8(v0*enc8);
            op8[c0 + 16 + l16] = f2fp8(v1*enc8);
          }
        }
      }
    }
  }
}

// ---- final combine ----
__global__ void k_combine(const u16* __restrict__ y, const float* __restrict__ probs,
                          float* __restrict__ out){
  int t = blockIdx.x*blockDim.x + threadIdx.x;
  if(t >= NN*HID) return;
  int n = t >> 7, j = t & 127;
  const u16* yp = y + (size_t)n*(NEXP*HID);
  const float* pp = probs + n*NEXP;
  float r = pp[0]*bf2f(yp[j]) + pp[1]*bf2f(yp[HID+j])
          + pp[2]*bf2f(yp[2*HID+j]) + pp[3]*bf2f(yp[3*HID+j]);
  out[t] = r;
}

extern "C" void kernel_launch(void* const* d_in, const int* in_sizes, int n_in,
                              void* d_out, int out_size, void* d_ws, size_t ws_size,
                              hipStream_t stream){
  const float* x      = (const float*)d_in[0];
  const int*   eidx   = (const int*)d_in[1];
  const int*   batch  = (const int*)d_in[2];
  const float* Wenc   = (const float*)d_in[3];
  const float* benc   = (const float*)d_in[4];
  const float* Wself  = (const float*)d_in[5];
  const float* Wnbr   = (const float*)d_in[6];
  const float* bconv  = (const float*)d_in[7];
  const float* centers= (const float*)d_in[8];
  float* out = (float*)d_out;
  const int* src = eidx;
  const int* dst = eidx + NE;

  char* w = (char*)d_ws;
  size_t off = 0;
  auto alloc = [&](size_t b)->char*{ char* p = w + off; off = (off + b + 255) & ~(size_t)255; return p; };

  u16* h0    = (u16*)alloc((size_t)NN*HID*2);        // 12.8 MB  } hB8 aliases
  u16* agg0  = (u16*)alloc((size_t)NN*HID*2);        // 12.8 MB  } these two
  u16* hA    = (u16*)alloc((size_t)NN*NEXP*HID*2);
  u16* hB    = (u16*)alloc((size_t)NN*NEXP*HID*2);
  u16* agg   = (u16*)alloc((size_t)NN*NEXP*HID*2);
  u16* WbfT  = (u16*)alloc((size_t)12*HID*256*2);
  u8*  h08   = (u8*)alloc((size_t)NN*HID);
  u8*  hA8   = (u8*)alloc((size_t)NN*NEXP*HID);
  float* probs = (float*)alloc((size_t)NN*NEXP*4);
  int* gstart = (int*)alloc(256);
  int* deg   = (int*)alloc((size_t)NN*4);
  int* offs  = (int*)alloc((size_t)(NN+1)*4);
  int* cursor= (int*)alloc((size_t)NN*4);
  int* srcs  = (int*)alloc((size_t)NE*4);
  int* bsum  = (int*)alloc((size_t)(NB_SCAN+1)*4);
  int* boff  = (int*)alloc((size_t)(NB_SCAN+1)*4);
  if(off > ws_size) return;
  // hB8 aliases h0+agg0 (dead after layer-0 GEMM; 12.8+12.8 = exactly 25.6 MB)
  u8* hB8 = (u8*)h0;

  hipMemsetAsync(deg, 0, (size_t)NN*4, stream);

  k_bounds<<<1, 32, 0, stream>>>(batch, gstart);
  k_probs<<<(NN+255)/256, 256, 0, stream>>>(batch, gstart, centers, probs);
  k_enc<<<(NN*HID+255)/256, 256, 0, stream>>>(x, Wenc, benc, h0, h08, 0.5f);
  k_wcvtT<<<(12*HID*256+255)/256, 256, 0, stream>>>(Wself, Wnbr, WbfT);
  k_deg<<<(NE+255)/256, 256, 0, stream>>>(dst, deg);
  k_scan1<<<NB_SCAN, 1024, 0, stream>>>(deg, offs, bsum);
  k_scan2<<<1, 64, 0, stream>>>(bsum, boff);
  k_scan3<<<(NN+1023)/1024, 1024, 0, stream>>>(offs, boff, cursor);
  k_fill<<<(NE+255)/256, 256, 0, stream>>>(src, dst, cursor, srcs);

  dim3 ggrid((NN + RPB - 1)/RPB, NEXP);

  // layer 0
  k_agg8<2><<<(NN+3)/4, 256, 0, stream>>>(h08, offs, srcs, agg0, 2.0f);
  k_gemm_mfma<true><<<ggrid, 256, 0, stream>>>(h0, agg0, HID, 0, WbfT, bconv, 0,
                                               hA, hA8, 1.f/16.f);
  // layer 1
  k_agg8<8><<<(NN+3)/4, 256, 0, stream>>>(hA8, offs, srcs, agg, 16.f);
  k_gemm_mfma<true><<<ggrid, 256, 0, stream>>>(hA, agg, NEXP*HID, HID, WbfT, bconv, 1,
                                               hB, hB8, 1.f/32.f);
  // layer 2 (no relu, no fp8 shadow)
  k_agg8<8><<<(NN+3)/4, 256, 0, stream>>>(hB8, offs, srcs, agg, 32.f);
  k_gemm_mfma<false><<<ggrid, 256, 0, stream>>>(hB, agg, NEXP*HID, HID, WbfT, bconv, 2,
                                                hA, (u8*)nullptr, 0.f);

  k_combine<<<(NN*HID+255)/256, 256, 0, stream>>>(hA, probs, out);
}

// Round 6
// 641.387 us; speedup vs baseline: 6.6568x; 1.1147x over previous
//
#include <hip/hip_runtime.h>

#define NN 50000
#define NE 1600000
#define NG 16
#define HID 128
#define NEXP 4
#define LOGN_SCALE 9.210340371976184f

#define NBUK 256     // dst buckets
#define NPB  196     // nodes per bucket (196*255=49980, last bucket has 20)
#define NBLK 64      // hist/scatter blocks
#define EPB  ((NE + NBLK - 1)/NBLK)   // 25000 edges per block
#define MAXB 16384   // LDS capacity per bucket (mean 6272, 6-sigma ~6750)

typedef unsigned short u16;
typedef unsigned int u32;
typedef unsigned char u8;
typedef __attribute__((ext_vector_type(8))) short short8b;   // 8 bf16 = 4 VGPR
typedef __attribute__((ext_vector_type(4))) float f32x4;
typedef __attribute__((ext_vector_type(2))) float f32x2;

static __device__ __forceinline__ float bf2f(u16 u){
  union { u32 i; float f; } c; c.i = ((u32)u)<<16; return c.f;
}
static __device__ __forceinline__ u16 f2bf(float f){
  union { float f; u32 i; } c; c.f = f;
  return (u16)((c.i + 0x7fffu + ((c.i>>16)&1u)) >> 16);
}
static __device__ __forceinline__ u8 f2fp8(float v){
  return (u8)(__builtin_amdgcn_cvt_pk_fp8_f32(v, v, 0, false) & 0xffu);
}

// ---- graph boundaries via binary search (batch is sorted) ----
__global__ void k_bounds(const int* __restrict__ batch, int* __restrict__ gstart){
  int g = threadIdx.x;
  if(g > NG) return;
  int lo = 0, hi = NN;
  while(lo < hi){ int mid = (lo+hi)>>1; if(batch[mid] < g) lo = mid+1; else hi = mid; }
  gstart[g] = lo;
}

// ---- per-node expert probs ----
__global__ void k_probs(const int* __restrict__ batch, const int* __restrict__ gstart,
                        const float* __restrict__ centers, float* __restrict__ probs){
  int n = blockIdx.x*blockDim.x + threadIdx.x;
  if(n >= NN) return;
  int b = batch[n];
  float c = (float)(gstart[b+1] - gstart[b]);
  float logn = logf(fmaxf(c, 1.f)) * (1.f/LOGN_SCALE);
  float s[NEXP]; float m = -1e30f;
  #pragma unroll
  for(int e=0;e<NEXP;e++){ float d = logn - centers[e]; s[e] = -d*d; m = fmaxf(m, s[e]); }
  float sum = 0.f;
  #pragma unroll
  for(int e=0;e<NEXP;e++){ s[e] = expf(s[e]-m); sum += s[e]; }
  float inv = 1.f/sum;
  #pragma unroll
  for(int e=0;e<NEXP;e++) probs[n*NEXP+e] = s[e]*inv;
}

// ---- encoder: h0 = relu(x @ Wenc + benc), bf16 + fp8 out ----
__global__ void k_enc(const float* __restrict__ x, const float* __restrict__ Wenc,
                      const float* __restrict__ benc, u16* __restrict__ h0,
                      u8* __restrict__ h08, float esc){
  int t = blockIdx.x*blockDim.x + threadIdx.x;
  if(t >= NN*HID) return;
  int n = t >> 7, j = t & 127;
  float acc = benc[j];
  #pragma unroll
  for(int k=0;k<6;k++) acc += x[n*6+k]*Wenc[k*HID+j];
  float v = fmaxf(acc, 0.f);
  h0[t] = f2bf(v);
  h08[t] = f2fp8(v*esc);
}

// ---- weights -> bf16, transposed+concatenated ----
__global__ void k_wcvtT(const float* __restrict__ Wself, const float* __restrict__ Wnbr,
                        u16* __restrict__ WbfT){
  int t = blockIdx.x*blockDim.x + threadIdx.x;
  if(t >= 12*HID*256) return;
  int el = t / (HID*256);
  int r  = t % (HID*256);
  int j  = r >> 8;
  int k  = r & 255;
  float v = (k < HID) ? Wself[(size_t)el*HID*HID + (size_t)k*HID + j]
                      : Wnbr [(size_t)el*HID*HID + (size_t)(k-HID)*HID + j];
  WbfT[t] = f2bf(v);
}

// ==== bucketed CSR build ====
// phase 1: per-block histogram over 256 dst-buckets
__global__ __launch_bounds__(256) void k_hist(const int* __restrict__ dst,
                                              int* __restrict__ hist){
  __shared__ int h[NBUK];
  for(int i=threadIdx.x; i<NBUK; i+=256) h[i] = 0;
  __syncthreads();
  int e0 = blockIdx.x*EPB, e1 = min(NE, e0 + EPB);
  for(int e = e0 + (int)threadIdx.x; e < e1; e += 256)
    atomicAdd(&h[dst[e]/NPB], 1);
  __syncthreads();
  for(int i=threadIdx.x; i<NBUK; i+=256) hist[blockIdx.x*NBUK + i] = h[i];
}

// phase 2: bucket-major exclusive scan of hist[NBLK][NBUK] (16384 ints)
__global__ __launch_bounds__(1024) void k_hscan(const int* __restrict__ hist,
                                                int* __restrict__ hoff,
                                                int* __restrict__ bbase){
  __shared__ int sd[NBLK*NBUK];
  __shared__ int ps[1024];
  int t = threadIdx.x;
  #pragma unroll
  for(int i=0;i<16;i++){
    int idx = t*16+i;                 // bucket-major: bucket=idx>>6, blk=idx&63
    sd[idx] = hist[(idx & (NBLK-1))*NBUK + (idx >> 6)];
  }
  __syncthreads();
  int sum = 0, base = t*16;
  #pragma unroll
  for(int i=0;i<16;i++){ int v = sd[base+i]; sd[base+i] = sum; sum += v; }
  ps[t] = sum;
  __syncthreads();
  for(int d=1; d<1024; d<<=1){
    int v = (t>=d) ? ps[t-d] : 0;
    __syncthreads();
    ps[t] += v;
    __syncthreads();
  }
  int add = (t>0) ? ps[t-1] : 0;
  #pragma unroll
  for(int i=0;i<16;i++){
    int idx = t*16+i;
    int bucket = idx>>6, blk = idx & (NBLK-1);
    int v = sd[idx] + add;
    hoff[blk*NBUK + bucket] = v;
    if(blk == 0) bbase[bucket] = v;
  }
  if(t == 1023) bbase[NBUK] = NE;
}

// phase 3: scatter packed (src | dstlow<<16) to bucket-sorted positions
__global__ __launch_bounds__(256) void k_scatter(const int* __restrict__ src,
                                                 const int* __restrict__ dst,
                                                 const int* __restrict__ hoff,
                                                 u32* __restrict__ packed){
  __shared__ u32 cur[NBUK];
  for(int i=threadIdx.x; i<NBUK; i+=256) cur[i] = (u32)hoff[blockIdx.x*NBUK + i];
  __syncthreads();
  int e0 = blockIdx.x*EPB, e1 = min(NE, e0 + EPB);
  for(int e = e0 + (int)threadIdx.x; e < e1; e += 256){
    int d = dst[e];
    int b = d/NPB;
    u32 p = atomicAdd(&cur[b], 1u);
    packed[p] = (u32)src[e] | ((u32)(d - b*NPB) << 16);
  }
}

// phase 4: per-bucket build of per-node CSR in LDS
__global__ __launch_bounds__(256) void k_build(const u32* __restrict__ packed,
                                               const int* __restrict__ bbase,
                                               int* __restrict__ offs,
                                               u16* __restrict__ srcs16){
  __shared__ u32 ent[MAXB];
  __shared__ u16 outb[MAXB];
  __shared__ u32 cnt[256], exc[256], cur[256];
  int b = blockIdx.x, t = threadIdx.x;
  int e0 = bbase[b], e1 = bbase[b+1];
  int len = e1 - e0, cap = min(len, MAXB);
  for(int i=t; i<cap; i+=256) ent[i] = packed[e0+i];
  cnt[t] = 0;
  __syncthreads();
  for(int i=t; i<len; i+=256){
    u32 v = (i < MAXB) ? ent[i] : packed[e0+i];
    atomicAdd(&cnt[v>>16], 1u);
  }
  __syncthreads();
  u32 c = cnt[t];
  exc[t] = c;
  __syncthreads();
  for(int d=1; d<256; d<<=1){
    u32 v = (t>=(u32)d) ? exc[t-d] : 0u;
    __syncthreads();
    exc[t] += v;
    __syncthreads();
  }
  u32 excl = exc[t] - c;
  int node = b*NPB + t;
  if(t < NPB && node < NN) offs[node] = e0 + (int)excl;
  cur[t] = excl;
  if(b == NBUK-1 && t == 0) offs[NN] = NE;
  __syncthreads();
  for(int i=t; i<len; i+=256){
    u32 v = (i < MAXB) ? ent[i] : packed[e0+i];
    u32 p = atomicAdd(&cur[v>>16], 1u);
    u16 sv = (u16)(v & 0xffffu);
    if(p < (u32)MAXB) outb[p] = sv;
    else srcs16[e0+p] = sv;
  }
  __syncthreads();
  for(int i=t; i<cap; i+=256) srcs16[e0+i] = outb[i];
}

// ---- aggregation over fp8 table: one wave per node, BPL bytes per lane ----
template<int BPL>
__global__ __launch_bounds__(256) void k_agg8(const u8* __restrict__ hin,
                                              const int* __restrict__ offs,
                                              const u16* __restrict__ srcs,
                                              u16* __restrict__ hout, float inv_scale){
  const int W = BPL*64;
  int node = blockIdx.x*4 + (threadIdx.x>>6);
  if(node >= NN) return;
  int lane = threadIdx.x & 63;
  const u8* hbase = hin + lane*BPL;
  float acc[BPL];
  #pragma unroll
  for(int i=0;i<BPL;i++) acc[i] = 0.f;
  int beg = offs[node], end = offs[node+1];
  for(int eb=beg; eb<end; eb+=64){
    int idx = eb + lane;
    int s = (idx < end) ? (int)srcs[idx] : 0;
    int cnt = min(64, end-eb);
    int j = 0;
    if(BPL == 8){
      for(; j+8<=cnt; j+=8){
        uint2 v[8];
        #pragma unroll
        for(int u=0;u<8;u++){
          int sj = __shfl(s, j+u, 64);
          v[u] = *(const uint2*)(hbase + (size_t)sj*W);
        }
        #pragma unroll
        for(int u=0;u<8;u++){
          f32x2 f0 = __builtin_amdgcn_cvt_pk_f32_fp8(v[u].x, false);
          f32x2 f1 = __builtin_amdgcn_cvt_pk_f32_fp8(v[u].x, true);
          f32x2 f2 = __builtin_amdgcn_cvt_pk_f32_fp8(v[u].y, false);
          f32x2 f3 = __builtin_amdgcn_cvt_pk_f32_fp8(v[u].y, true);
          acc[0]+=f0.x; acc[1]+=f0.y; acc[2]+=f1.x; acc[3]+=f1.y;
          acc[4]+=f2.x; acc[5]+=f2.y; acc[6]+=f3.x; acc[7]+=f3.y;
        }
      }
      for(; j<cnt; j++){
        int sj = __shfl(s, j, 64);
        uint2 v = *(const uint2*)(hbase + (size_t)sj*W);
        f32x2 f0 = __builtin_amdgcn_cvt_pk_f32_fp8(v.x, false);
        f32x2 f1 = __builtin_amdgcn_cvt_pk_f32_fp8(v.x, true);
        f32x2 f2 = __builtin_amdgcn_cvt_pk_f32_fp8(v.y, false);
        f32x2 f3 = __builtin_amdgcn_cvt_pk_f32_fp8(v.y, true);
        acc[0]+=f0.x; acc[1]+=f0.y; acc[2]+=f1.x; acc[3]+=f1.y;
        acc[4]+=f2.x; acc[5]+=f2.y; acc[6]+=f3.x; acc[7]+=f3.y;
      }
    } else {
      for(; j+8<=cnt; j+=8){
        u32 v[8];
        #pragma unroll
        for(int u=0;u<8;u++){
          int sj = __shfl(s, j+u, 64);
          v[u] = *(const u16*)(hbase + (size_t)sj*W);
        }
        #pragma unroll
        for(int u=0;u<8;u++){
          f32x2 f0 = __builtin_amdgcn_cvt_pk_f32_fp8(v[u], false);
          acc[0]+=f0.x; acc[1]+=f0.y;
        }
      }
      for(; j<cnt; j++){
        int sj = __shfl(s, j, 64);
        u32 v = *(const u16*)(hbase + (size_t)sj*W);
        f32x2 f0 = __builtin_amdgcn_cvt_pk_f32_fp8(v, false);
        acc[0]+=f0.x; acc[1]+=f0.y;
      }
    }
  }
  u16* o = hout + (size_t)node*W + lane*BPL;
  #pragma unroll
  for(int i=0;i<BPL;i++) o[i] = f2bf(acc[i]*inv_scale);
}

// ---- MFMA dual GEMM ----
#define RPB 256
template<bool RELU>
__global__ __launch_bounds__(256) void k_gemm_mfma(
    const u16* __restrict__ hin, const u16* __restrict__ aggin,
    int in_stride, int in_eoff,
    const u16* __restrict__ WbfT, const float* __restrict__ bconv,
    int layer, u16* __restrict__ hout, u8* __restrict__ hout8, float enc8)
{
  int e = blockIdx.y;
  int wave = threadIdx.x >> 6, lane = threadIdx.x & 63;
  int l16 = lane & 15, lq = lane >> 4;
  int c0 = wave*32;
  const u16* WT = WbfT + (size_t)((e*3+layer)*HID)*256;

  short8b Bf[2][8];
  #pragma unroll
  for(int ct=0; ct<2; ct++){
    const u16* wp = WT + (size_t)(c0 + ct*16 + l16)*256 + lq*8;
    #pragma unroll
    for(int ks=0; ks<8; ks++)
      Bf[ct][ks] = *(const short8b*)(wp + ks*32);
  }
  const float* bias = bconv + (e*3+layer)*HID;
  float b0 = bias[c0 + l16], b1 = bias[c0 + 16 + l16];

  int nbase = blockIdx.x * RPB;
  #pragma unroll 1
  for(int it=0; it<RPB/32; it++){
    int n0 = nbase + it*32;
    if(n0 >= NN) break;
    f32x4 acc[2][2];
    #pragma unroll
    for(int rt=0; rt<2; rt++){
      acc[rt][0] = (f32x4){b0,b0,b0,b0};
      acc[rt][1] = (f32x4){b1,b1,b1,b1};
    }
    #pragma unroll
    for(int ks=0; ks<8; ks++){
      #pragma unroll
      for(int rt=0; rt<2; rt++){
        int n = n0 + rt*16 + l16;
        if(n > NN-1) n = NN-1;
        const u16* base = (ks < 4)
            ? (hin   + (size_t)n*in_stride + (size_t)e*in_eoff)
            : (aggin + (size_t)n*in_stride + (size_t)e*in_eoff - 128);
        short8b Af = *(const short8b*)(base + ks*32 + lq*8);
        acc[rt][0] = __builtin_amdgcn_mfma_f32_16x16x32_bf16(Af, Bf[0][ks], acc[rt][0], 0,0,0);
        acc[rt][1] = __builtin_amdgcn_mfma_f32_16x16x32_bf16(Af, Bf[1][ks], acc[rt][1], 0,0,0);
      }
    }
    #pragma unroll
    for(int rt=0; rt<2; rt++){
      int rowb = n0 + rt*16 + lq*4;
      #pragma unroll
      for(int r=0; r<4; r++){
        int n = rowb + r;
        if(n < NN){
          float v0 = acc[rt][0][r], v1 = acc[rt][1][r];
          if(RELU){ v0 = fmaxf(v0, 0.f); v1 = fmaxf(v1, 0.f); }
          u16* op = hout + (size_t)n*(NEXP*HID) + e*HID;
          op[c0 + l16]      = f2bf(v0);
          op[c0 + 16 + l16] = f2bf(v1);
          if(hout8){
            u8* op8 = hout8 + (size_t)n*(NEXP*HID) + e*HID;
            op8[c0 + l16]      = f2fp8(v0*enc8);
            op8[c0 + 16 + l16] = f2fp8(v1*enc8);
          }
        }
      }
    }
  }
}

// ---- final combine ----
__global__ void k_combine(const u16* __restrict__ y, const float* __restrict__ probs,
                          float* __restrict__ out){
  int t = blockIdx.x*blockDim.x + threadIdx.x;
  if(t >= NN*HID) return;
  int n = t >> 7, j = t & 127;
  const u16* yp = y + (size_t)n*(NEXP*HID);
  const float* pp = probs + n*NEXP;
  float r = pp[0]*bf2f(yp[j]) + pp[1]*bf2f(yp[HID+j])
          + pp[2]*bf2f(yp[2*HID+j]) + pp[3]*bf2f(yp[3*HID+j]);
  out[t] = r;
}

extern "C" void kernel_launch(void* const* d_in, const int* in_sizes, int n_in,
                              void* d_out, int out_size, void* d_ws, size_t ws_size,
                              hipStream_t stream){
  const float* x      = (const float*)d_in[0];
  const int*   eidx   = (const int*)d_in[1];
  const int*   batch  = (const int*)d_in[2];
  const float* Wenc   = (const float*)d_in[3];
  const float* benc   = (const float*)d_in[4];
  const float* Wself  = (const float*)d_in[5];
  const float* Wnbr   = (const float*)d_in[6];
  const float* bconv  = (const float*)d_in[7];
  const float* centers= (const float*)d_in[8];
  float* out = (float*)d_out;
  const int* src = eidx;
  const int* dst = eidx + NE;

  char* w = (char*)d_ws;
  size_t off = 0;
  auto alloc = [&](size_t b)->char*{ char* p = w + off; off = (off + b + 255) & ~(size_t)255; return p; };

  u16* h0    = (u16*)alloc((size_t)NN*HID*2);        // 12.8 MB } hB8 aliases
  u16* agg0  = (u16*)alloc((size_t)NN*HID*2);        // 12.8 MB } these two
  u16* hA    = (u16*)alloc((size_t)NN*NEXP*HID*2);
  u16* hB    = (u16*)alloc((size_t)NN*NEXP*HID*2);
  u16* agg   = (u16*)alloc((size_t)NN*NEXP*HID*2);
  u16* WbfT  = (u16*)alloc((size_t)12*HID*256*2);
  u8*  h08   = (u8*)alloc((size_t)NN*HID);
  u8*  hA8   = (u8*)alloc((size_t)NN*NEXP*HID);
  float* probs = (float*)alloc((size_t)NN*NEXP*4);
  int* gstart = (int*)alloc(256);
  int* offs  = (int*)alloc((size_t)(NN+1)*4);
  u32* packed= (u32*)alloc((size_t)NE*4);
  u16* srcs16= (u16*)alloc((size_t)NE*2);
  int* hist  = (int*)alloc((size_t)NBLK*NBUK*4);
  int* hoff  = (int*)alloc((size_t)NBLK*NBUK*4);
  int* bbase = (int*)alloc((size_t)(NBUK+1)*4);
  if(off > ws_size) return;
  u8* hB8 = (u8*)h0;   // aliases h0+agg0 (dead after layer-0 GEMM)

  k_bounds<<<1, 32, 0, stream>>>(batch, gstart);
  k_probs<<<(NN+255)/256, 256, 0, stream>>>(batch, gstart, centers, probs);
  k_enc<<<(NN*HID+255)/256, 256, 0, stream>>>(x, Wenc, benc, h0, h08, 0.5f);
  k_wcvtT<<<(12*HID*256+255)/256, 256, 0, stream>>>(Wself, Wnbr, WbfT);

  k_hist<<<NBLK, 256, 0, stream>>>(dst, hist);
  k_hscan<<<1, 1024, 0, stream>>>(hist, hoff, bbase);
  k_scatter<<<NBLK, 256, 0, stream>>>(src, dst, hoff, packed);
  k_build<<<NBUK, 256, 0, stream>>>(packed, bbase, offs, srcs16);

  dim3 ggrid((NN + RPB - 1)/RPB, NEXP);

  // layer 0
  k_agg8<2><<<(NN+3)/4, 256, 0, stream>>>(h08, offs, srcs16, agg0, 2.0f);
  k_gemm_mfma<true><<<ggrid, 256, 0, stream>>>(h0, agg0, HID, 0, WbfT, bconv, 0,
                                               hA, hA8, 1.f/16.f);
  // layer 1
  k_agg8<8><<<(NN+3)/4, 256, 0, stream>>>(hA8, offs, srcs16, agg, 16.f);
  k_gemm_mfma<true><<<ggrid, 256, 0, stream>>>(hA, agg, NEXP*HID, HID, WbfT, bconv, 1,
                                               hB, hB8, 1.f/32.f);
  // layer 2 (no relu, no fp8 shadow)
  k_agg8<8><<<(NN+3)/4, 256, 0, stream>>>(hB8, offs, srcs16, agg, 32.f);
  k_gemm_mfma<false><<<ggrid, 256, 0, stream>>>(hB, agg, NEXP*HID, HID, WbfT, bconv, 2,
                                                hA, (u8*)nullptr, 0.f);

  k_combine<<<(NN*HID+255)/256, 256, 0, stream>>>(hA, probs, out);
}

// Round 7
// 611.901 us; speedup vs baseline: 6.9776x; 1.0482x over previous
//
#include <hip/hip_runtime.h>

#define NN 50000
#define NE 1600000
#define NG 16
#define HID 128
#define NEXP 4
#define LOGN_SCALE 9.210340371976184f

#define NBUK 256     // dst buckets
#define NPB  196     // nodes per bucket (196*255=49980, last bucket has 20)
#define NBLK 128     // hist/scatter blocks
#define EPB  ((NE + NBLK - 1)/NBLK)   // 12500 edges per block
#define MAXB 16384   // k_build LDS capacity per bucket (mean 6272)

typedef unsigned short u16;
typedef unsigned int u32;
typedef unsigned char u8;
typedef __attribute__((ext_vector_type(8))) short short8b;   // 8 bf16 = 4 VGPR
typedef __attribute__((ext_vector_type(4))) float f32x4;
typedef __attribute__((ext_vector_type(2))) float f32x2;

static __device__ __forceinline__ float bf2f(u16 u){
  union { u32 i; float f; } c; c.i = ((u32)u)<<16; return c.f;
}
static __device__ __forceinline__ u16 f2bf(float f){
  union { float f; u32 i; } c; c.f = f;
  return (u16)((c.i + 0x7fffu + ((c.i>>16)&1u)) >> 16);
}
static __device__ __forceinline__ u8 f2fp8(float v){
  return (u8)(__builtin_amdgcn_cvt_pk_fp8_f32(v, v, 0, false) & 0xffu);
}

// ---- graph boundaries via binary search (batch is sorted) ----
__global__ void k_bounds(const int* __restrict__ batch, int* __restrict__ gstart){
  int g = threadIdx.x;
  if(g > NG) return;
  int lo = 0, hi = NN;
  while(lo < hi){ int mid = (lo+hi)>>1; if(batch[mid] < g) lo = mid+1; else hi = mid; }
  gstart[g] = lo;
}

// ---- per-node expert probs ----
__global__ void k_probs(const int* __restrict__ batch, const int* __restrict__ gstart,
                        const float* __restrict__ centers, float* __restrict__ probs){
  int n = blockIdx.x*blockDim.x + threadIdx.x;
  if(n >= NN) return;
  int b = batch[n];
  float c = (float)(gstart[b+1] - gstart[b]);
  float logn = logf(fmaxf(c, 1.f)) * (1.f/LOGN_SCALE);
  float s[NEXP]; float m = -1e30f;
  #pragma unroll
  for(int e=0;e<NEXP;e++){ float d = logn - centers[e]; s[e] = -d*d; m = fmaxf(m, s[e]); }
  float sum = 0.f;
  #pragma unroll
  for(int e=0;e<NEXP;e++){ s[e] = expf(s[e]-m); sum += s[e]; }
  float inv = 1.f/sum;
  #pragma unroll
  for(int e=0;e<NEXP;e++) probs[n*NEXP+e] = s[e]*inv;
}

// ---- encoder: h0 = relu(x @ Wenc + benc), bf16 + fp8 out ----
__global__ void k_enc(const float* __restrict__ x, const float* __restrict__ Wenc,
                      const float* __restrict__ benc, u16* __restrict__ h0,
                      u8* __restrict__ h08, float esc){
  int t = blockIdx.x*blockDim.x + threadIdx.x;
  if(t >= NN*HID) return;
  int n = t >> 7, j = t & 127;
  float acc = benc[j];
  #pragma unroll
  for(int k=0;k<6;k++) acc += x[n*6+k]*Wenc[k*HID+j];
  float v = fmaxf(acc, 0.f);
  h0[t] = f2bf(v);
  h08[t] = f2fp8(v*esc);
}

// ---- weights -> bf16, transposed+concatenated ----
__global__ void k_wcvtT(const float* __restrict__ Wself, const float* __restrict__ Wnbr,
                        u16* __restrict__ WbfT){
  int t = blockIdx.x*blockDim.x + threadIdx.x;
  if(t >= 12*HID*256) return;
  int el = t / (HID*256);
  int r  = t % (HID*256);
  int j  = r >> 8;
  int k  = r & 255;
  float v = (k < HID) ? Wself[(size_t)el*HID*HID + (size_t)k*HID + j]
                      : Wnbr [(size_t)el*HID*HID + (size_t)(k-HID)*HID + j];
  WbfT[t] = f2bf(v);
}

// ==== bucketed CSR build ====
// phase 1: per-block histogram over 256 dst-buckets
__global__ __launch_bounds__(256) void k_hist(const int* __restrict__ dst,
                                              int* __restrict__ hist){
  __shared__ int h[NBUK];
  for(int i=threadIdx.x; i<NBUK; i+=256) h[i] = 0;
  __syncthreads();
  int e0 = blockIdx.x*EPB, e1 = min(NE, e0 + EPB);
  for(int e = e0 + (int)threadIdx.x; e < e1; e += 256)
    atomicAdd(&h[dst[e]/NPB], 1);
  __syncthreads();
  for(int i=threadIdx.x; i<NBUK; i+=256) hist[blockIdx.x*NBUK + i] = h[i];
}

// phase 2: bucket-major exclusive scan of hist[NBLK][NBUK] (32768 ints)
// serial-32 per thread + one 1024-scan
__global__ __launch_bounds__(1024) void k_hscan(const int* __restrict__ hist,
                                                int* __restrict__ hoff,
                                                int* __restrict__ bbase){
  __shared__ int sd[NBLK*NBUK];   // 128 KB
  __shared__ int ps[1024];
  int t = threadIdx.x;
  for(int i=t; i<NBLK*NBUK; i+=1024){
    int bucket = i >> 7;          // / NBLK
    int blk = i & (NBLK-1);
    sd[i] = hist[blk*NBUK + bucket];
  }
  __syncthreads();
  int base = t*32, sum = 0;
  #pragma unroll
  for(int i=0;i<32;i++){ int v = sd[base+i]; sd[base+i] = sum; sum += v; }
  ps[t] = sum;
  __syncthreads();
  for(int d=1; d<1024; d<<=1){
    int v = (t>=d) ? ps[t-d] : 0;
    __syncthreads();
    ps[t] += v;
    __syncthreads();
  }
  int add = (t>0) ? ps[t-1] : 0;
  for(int i=base; i<base+32; i++){
    int bucket = i >> 7, blk = i & (NBLK-1);
    int v = sd[i] + add;
    hoff[blk*NBUK + bucket] = v;
    if(blk == 0) bbase[bucket] = v;
  }
  if(t == 1023) bbase[NBUK] = NE;
}

// phase 3: LDS counting-sort per block, coalesced run writes.
// packed entry: src (bits 0-15) | dstlow (16-23); bucket in 24-31 only inside LDS.
__global__ __launch_bounds__(256) void k_scatter(const int* __restrict__ src,
                                                 const int* __restrict__ dst,
                                                 const int* __restrict__ hoff,
                                                 u32* __restrict__ packed){
  __shared__ u32 ent[EPB];    // 50 KB
  __shared__ u32 outp[EPB];   // 50 KB
  __shared__ u32 cnt[NBUK], exc[NBUK], cur[NBUK], gb[NBUK];
  int t = threadIdx.x;
  int e0 = blockIdx.x*EPB;
  int len = min(EPB, NE - e0);
  cnt[t] = 0;
  __syncthreads();
  for(int i=t; i<len; i+=256){
    int d = dst[e0+i];
    u32 b = (u32)(d/NPB);
    ent[i] = (u32)src[e0+i] | ((u32)(d - (int)b*NPB) << 16) | (b << 24);
    atomicAdd(&cnt[b], 1u);
  }
  __syncthreads();
  u32 c = cnt[t];
  exc[t] = c;
  __syncthreads();
  for(int d=1; d<256; d<<=1){
    u32 v = (t>=(u32)d) ? exc[t-d] : 0u;
    __syncthreads();
    exc[t] += v;
    __syncthreads();
  }
  u32 excl = exc[t] - c;
  cur[t] = excl;
  gb[t] = (u32)hoff[blockIdx.x*NBUK + t];
  __syncthreads();
  exc[t] = excl;               // save exclusive base
  __syncthreads();
  for(int i=t; i<len; i+=256){
    u32 v = ent[i];
    u32 p = atomicAdd(&cur[v>>24], 1u);
    outp[p] = v;
  }
  __syncthreads();
  for(int i=t; i<len; i+=256){
    u32 v = outp[i];
    u32 b = v >> 24;
    packed[gb[b] + ((u32)i - exc[b])] = v & 0x00ffffffu;
  }
}

// phase 4: per-bucket build of per-node CSR in LDS
__global__ __launch_bounds__(256) void k_build(const u32* __restrict__ packed,
                                               const int* __restrict__ bbase,
                                               int* __restrict__ offs,
                                               u16* __restrict__ srcs16){
  __shared__ u32 ent[MAXB];
  __shared__ u16 outb[MAXB];
  __shared__ u32 cnt[256], exc[256], cur[256];
  int b = blockIdx.x, t = threadIdx.x;
  int e0 = bbase[b], e1 = bbase[b+1];
  int len = e1 - e0, cap = min(len, MAXB);
  for(int i=t; i<cap; i+=256) ent[i] = packed[e0+i];
  cnt[t] = 0;
  __syncthreads();
  for(int i=t; i<len; i+=256){
    u32 v = (i < MAXB) ? ent[i] : packed[e0+i];
    atomicAdd(&cnt[(v>>16)&0xffu], 1u);
  }
  __syncthreads();
  u32 c = cnt[t];
  exc[t] = c;
  __syncthreads();
  for(int d=1; d<256; d<<=1){
    u32 v = (t>=(u32)d) ? exc[t-d] : 0u;
    __syncthreads();
    exc[t] += v;
    __syncthreads();
  }
  u32 excl = exc[t] - c;
  int node = b*NPB + t;
  if(t < NPB && node < NN) offs[node] = e0 + (int)excl;
  cur[t] = excl;
  if(b == NBUK-1 && t == 0) offs[NN] = NE;
  __syncthreads();
  for(int i=t; i<len; i+=256){
    u32 v = (i < MAXB) ? ent[i] : packed[e0+i];
    u32 p = atomicAdd(&cur[(v>>16)&0xffu], 1u);
    u16 sv = (u16)(v & 0xffffu);
    if(p < (u32)MAXB) outb[p] = sv;
    else srcs16[e0+p] = sv;
  }
  __syncthreads();
  for(int i=t; i<cap; i+=256) srcs16[e0+i] = outb[i];
}

// ---- aggregation over fp8 table: one wave per node, BPL bytes per lane ----
template<int BPL>
__global__ __launch_bounds__(256) void k_agg8(const u8* __restrict__ hin,
                                              const int* __restrict__ offs,
                                              const u16* __restrict__ srcs,
                                              u16* __restrict__ hout, float inv_scale){
  const int W = BPL*64;
  int node = blockIdx.x*4 + (threadIdx.x>>6);
  if(node >= NN) return;
  int lane = threadIdx.x & 63;
  const u8* hbase = hin + lane*BPL;
  float acc[BPL];
  #pragma unroll
  for(int i=0;i<BPL;i++) acc[i] = 0.f;
  int beg = offs[node], end = offs[node+1];
  for(int eb=beg; eb<end; eb+=64){
    int idx = eb + lane;
    int s = (idx < end) ? (int)srcs[idx] : 0;
    int cnt = min(64, end-eb);
    int j = 0;
    if(BPL == 8){
      for(; j+8<=cnt; j+=8){
        uint2 v[8];
        #pragma unroll
        for(int u=0;u<8;u++){
          int sj = __shfl(s, j+u, 64);
          v[u] = *(const uint2*)(hbase + (size_t)sj*W);
        }
        #pragma unroll
        for(int u=0;u<8;u++){
          f32x2 f0 = __builtin_amdgcn_cvt_pk_f32_fp8(v[u].x, false);
          f32x2 f1 = __builtin_amdgcn_cvt_pk_f32_fp8(v[u].x, true);
          f32x2 f2 = __builtin_amdgcn_cvt_pk_f32_fp8(v[u].y, false);
          f32x2 f3 = __builtin_amdgcn_cvt_pk_f32_fp8(v[u].y, true);
          acc[0]+=f0.x; acc[1]+=f0.y; acc[2]+=f1.x; acc[3]+=f1.y;
          acc[4]+=f2.x; acc[5]+=f2.y; acc[6]+=f3.x; acc[7]+=f3.y;
        }
      }
      for(; j<cnt; j++){
        int sj = __shfl(s, j, 64);
        uint2 v = *(const uint2*)(hbase + (size_t)sj*W);
        f32x2 f0 = __builtin_amdgcn_cvt_pk_f32_fp8(v.x, false);
        f32x2 f1 = __builtin_amdgcn_cvt_pk_f32_fp8(v.x, true);
        f32x2 f2 = __builtin_amdgcn_cvt_pk_f32_fp8(v.y, false);
        f32x2 f3 = __builtin_amdgcn_cvt_pk_f32_fp8(v.y, true);
        acc[0]+=f0.x; acc[1]+=f0.y; acc[2]+=f1.x; acc[3]+=f1.y;
        acc[4]+=f2.x; acc[5]+=f2.y; acc[6]+=f3.x; acc[7]+=f3.y;
      }
    } else {
      for(; j+8<=cnt; j+=8){
        u32 v[8];
        #pragma unroll
        for(int u=0;u<8;u++){
          int sj = __shfl(s, j+u, 64);
          v[u] = *(const u16*)(hbase + (size_t)sj*W);
        }
        #pragma unroll
        for(int u=0;u<8;u++){
          f32x2 f0 = __builtin_amdgcn_cvt_pk_f32_fp8(v[u], false);
          acc[0]+=f0.x; acc[1]+=f0.y;
        }
      }
      for(; j<cnt; j++){
        int sj = __shfl(s, j, 64);
        u32 v = *(const u16*)(hbase + (size_t)sj*W);
        f32x2 f0 = __builtin_amdgcn_cvt_pk_f32_fp8(v, false);
        acc[0]+=f0.x; acc[1]+=f0.y;
      }
    }
  }
  u16* o = hout + (size_t)node*W + lane*BPL;
  #pragma unroll
  for(int i=0;i<BPL;i++) o[i] = f2bf(acc[i]*inv_scale);
}

// ---- MFMA dual GEMM ----
#define RPB 256
template<bool RELU>
__global__ __launch_bounds__(256) void k_gemm_mfma(
    const u16* __restrict__ hin, const u16* __restrict__ aggin,
    int in_stride, int in_eoff,
    const u16* __restrict__ WbfT, const float* __restrict__ bconv,
    int layer, u16* __restrict__ hout, u8* __restrict__ hout8, float enc8)
{
  int e = blockIdx.y;
  int wave = threadIdx.x >> 6, lane = threadIdx.x & 63;
  int l16 = lane & 15, lq = lane >> 4;
  int c0 = wave*32;
  const u16* WT = WbfT + (size_t)((e*3+layer)*HID)*256;

  short8b Bf[2][8];
  #pragma unroll
  for(int ct=0; ct<2; ct++){
    const u16* wp = WT + (size_t)(c0 + ct*16 + l16)*256 + lq*8;
    #pragma unroll
    for(int ks=0; ks<8; ks++)
      Bf[ct][ks] = *(const short8b*)(wp + ks*32);
  }
  const float* bias = bconv + (e*3+layer)*HID;
  float b0 = bias[c0 + l16], b1 = bias[c0 + 16 + l16];

  int nbase = blockIdx.x * RPB;
  #pragma unroll 1
  for(int it=0; it<RPB/32; it++){
    int n0 = nbase + it*32;
    if(n0 >= NN) break;
    f32x4 acc[2][2];
    #pragma unroll
    for(int rt=0; rt<2; rt++){
      acc[rt][0] = (f32x4){b0,b0,b0,b0};
      acc[rt][1] = (f32x4){b1,b1,b1,b1};
    }
    #pragma unroll
    for(int ks=0; ks<8; ks++){
      #pragma unroll
      for(int rt=0; rt<2; rt++){
        int n = n0 + rt*16 + l16;
        if(n > NN-1) n = NN-1;
        const u16* base = (ks < 4)
            ? (hin   + (size_t)n*in_stride + (size_t)e*in_eoff)
            : (aggin + (size_t)n*in_stride + (size_t)e*in_eoff - 128);
        short8b Af = *(const short8b*)(base + ks*32 + lq*8);
        acc[rt][0] = __builtin_amdgcn_mfma_f32_16x16x32_bf16(Af, Bf[0][ks], acc[rt][0], 0,0,0);
        acc[rt][1] = __builtin_amdgcn_mfma_f32_16x16x32_bf16(Af, Bf[1][ks], acc[rt][1], 0,0,0);
      }
    }
    #pragma unroll
    for(int rt=0; rt<2; rt++){
      int rowb = n0 + rt*16 + lq*4;
      #pragma unroll
      for(int r=0; r<4; r++){
        int n = rowb + r;
        if(n < NN){
          float v0 = acc[rt][0][r], v1 = acc[rt][1][r];
          if(RELU){ v0 = fmaxf(v0, 0.f); v1 = fmaxf(v1, 0.f); }
          u16* op = hout + (size_t)n*(NEXP*HID) + e*HID;
          op[c0 + l16]      = f2bf(v0);
          op[c0 + 16 + l16] = f2bf(v1);
          if(hout8){
            u8* op8 = hout8 + (size_t)n*(NEXP*HID) + e*HID;
            op8[c0 + l16]      = f2fp8(v0*enc8);
            op8[c0 + 16 + l16] = f2fp8(v1*enc8);
          }
        }
      }
    }
  }
}

// ---- final combine ----
__global__ void k_combine(const u16* __restrict__ y, const float* __restrict__ probs,
                          float* __restrict__ out){
  int t = blockIdx.x*blockDim.x + threadIdx.x;
  if(t >= NN*HID) return;
  int n = t >> 7, j = t & 127;
  const u16* yp = y + (size_t)n*(NEXP*HID);
  const float* pp = probs + n*NEXP;
  float r = pp[0]*bf2f(yp[j]) + pp[1]*bf2f(yp[HID+j])
          + pp[2]*bf2f(yp[2*HID+j]) + pp[3]*bf2f(yp[3*HID+j]);
  out[t] = r;
}

extern "C" void kernel_launch(void* const* d_in, const int* in_sizes, int n_in,
                              void* d_out, int out_size, void* d_ws, size_t ws_size,
                              hipStream_t stream){
  const float* x      = (const float*)d_in[0];
  const int*   eidx   = (const int*)d_in[1];
  const int*   batch  = (const int*)d_in[2];
  const float* Wenc   = (const float*)d_in[3];
  const float* benc   = (const float*)d_in[4];
  const float* Wself  = (const float*)d_in[5];
  const float* Wnbr   = (const float*)d_in[6];
  const float* bconv  = (const float*)d_in[7];
  const float* centers= (const float*)d_in[8];
  float* out = (float*)d_out;
  const int* src = eidx;
  const int* dst = eidx + NE;

  char* w = (char*)d_ws;
  size_t off = 0;
  auto alloc = [&](size_t b)->char*{ char* p = w + off; off = (off + b + 255) & ~(size_t)255; return p; };

  u16* h0    = (u16*)alloc((size_t)NN*HID*2);        // 12.8 MB } hB8 aliases
  u16* agg0  = (u16*)alloc((size_t)NN*HID*2);        // 12.8 MB } these two
  u16* hA    = (u16*)alloc((size_t)NN*NEXP*HID*2);
  u16* hB    = (u16*)alloc((size_t)NN*NEXP*HID*2);
  u16* agg   = (u16*)alloc((size_t)NN*NEXP*HID*2);
  u16* WbfT  = (u16*)alloc((size_t)12*HID*256*2);
  u8*  h08   = (u8*)alloc((size_t)NN*HID);
  u8*  hA8   = (u8*)alloc((size_t)NN*NEXP*HID);
  float* probs = (float*)alloc((size_t)NN*NEXP*4);
  int* gstart = (int*)alloc(256);
  int* offs  = (int*)alloc((size_t)(NN+1)*4);
  u32* packed= (u32*)alloc((size_t)NE*4);
  u16* srcs16= (u16*)alloc((size_t)NE*2);
  int* hist  = (int*)alloc((size_t)NBLK*NBUK*4);
  int* hoff  = (int*)alloc((size_t)NBLK*NBUK*4);
  int* bbase = (int*)alloc((size_t)(NBUK+1)*4);
  if(off > ws_size) return;
  u8* hB8 = (u8*)h0;   // aliases h0+agg0 (dead after layer-0 GEMM)

  k_bounds<<<1, 32, 0, stream>>>(batch, gstart);
  k_probs<<<(NN+255)/256, 256, 0, stream>>>(batch, gstart, centers, probs);
  k_enc<<<(NN*HID+255)/256, 256, 0, stream>>>(x, Wenc, benc, h0, h08, 0.5f);
  k_wcvtT<<<(12*HID*256+255)/256, 256, 0, stream>>>(Wself, Wnbr, WbfT);

  k_hist<<<NBLK, 256, 0, stream>>>(dst, hist);
  k_hscan<<<1, 1024, 0, stream>>>(hist, hoff, bbase);
  k_scatter<<<NBLK, 256, 0, stream>>>(src, dst, hoff, packed);
  k_build<<<NBUK, 256, 0, stream>>>(packed, bbase, offs, srcs16);

  dim3 ggrid((NN + RPB - 1)/RPB, NEXP);

  // layer 0
  k_agg8<2><<<(NN+3)/4, 256, 0, stream>>>(h08, offs, srcs16, agg0, 2.0f);
  k_gemm_mfma<true><<<ggrid, 256, 0, stream>>>(h0, agg0, HID, 0, WbfT, bconv, 0,
                                               hA, hA8, 1.f/16.f);
  // layer 1
  k_agg8<8><<<(NN+3)/4, 256, 0, stream>>>(hA8, offs, srcs16, agg, 16.f);
  k_gemm_mfma<true><<<ggrid, 256, 0, stream>>>(hA, agg, NEXP*HID, HID, WbfT, bconv, 1,
                                               hB, hB8, 1.f/32.f);
  // layer 2 (no relu, no fp8 shadow)
  k_agg8<8><<<(NN+3)/4, 256, 0, stream>>>(hB8, offs, srcs16, agg, 32.f);
  k_gemm_mfma<false><<<ggrid, 256, 0, stream>>>(hB, agg, NEXP*HID, HID, WbfT, bconv, 2,
                                                hA, (u8*)nullptr, 0.f);

  k_combine<<<(NN*HID+255)/256, 256, 0, stream>>>(hA, probs, out);
}

// Round 9
// 570.067 us; speedup vs baseline: 7.4897x; 1.0734x over previous
//
#include <hip/hip_runtime.h>

#define NN 50000
#define NE 1600000
#define NG 16
#define HID 128
#define NEXP 4
#define LOGN_SCALE 9.210340371976184f

#define NBUK 256     // dst buckets
#define NPB  196     // nodes per bucket
#define NBLK 128     // hist/scatter blocks
#define EPB  ((NE + NBLK - 1)/NBLK)   // 12500 edges per block
#define MAXB 16384   // k_build LDS capacity per bucket (mean 6272)

typedef unsigned short u16;
typedef unsigned int u32;
typedef unsigned char u8;
typedef __attribute__((ext_vector_type(8))) short short8b;   // 8 bf16 = 4 VGPR
typedef __attribute__((ext_vector_type(4))) float f32x4;
typedef __attribute__((ext_vector_type(2))) float f32x2;

static __device__ __forceinline__ float bf2f(u16 u){
  union { u32 i; float f; } c; c.i = ((u32)u)<<16; return c.f;
}
static __device__ __forceinline__ u16 f2bf(float f){
  union { float f; u32 i; } c; c.f = f;
  return (u16)((c.i + 0x7fffu + ((c.i>>16)&1u)) >> 16);
}
static __device__ __forceinline__ u8 f2fp8(float v){
  return (u8)(__builtin_amdgcn_cvt_pk_fp8_f32(v, v, 0, false) & 0xffu);
}
// 8 packed fp8 -> 8 bf16 (table units)
static __device__ __forceinline__ short8b fp8x8_to_bf16(uint2 v){
  f32x2 a = __builtin_amdgcn_cvt_pk_f32_fp8(v.x, false);
  f32x2 b = __builtin_amdgcn_cvt_pk_f32_fp8(v.x, true);
  f32x2 c = __builtin_amdgcn_cvt_pk_f32_fp8(v.y, false);
  f32x2 d = __builtin_amdgcn_cvt_pk_f32_fp8(v.y, true);
  short8b t;
  t[0]=(short)f2bf(a.x); t[1]=(short)f2bf(a.y);
  t[2]=(short)f2bf(b.x); t[3]=(short)f2bf(b.y);
  t[4]=(short)f2bf(c.x); t[5]=(short)f2bf(c.y);
  t[6]=(short)f2bf(d.x); t[7]=(short)f2bf(d.y);
  return t;
}

// ---- graph boundaries via binary search (batch is sorted) ----
__global__ void k_bounds(const int* __restrict__ batch, int* __restrict__ gstart){
  int g = threadIdx.x;
  if(g > NG) return;
  int lo = 0, hi = NN;
  while(lo < hi){ int mid = (lo+hi)>>1; if(batch[mid] < g) lo = mid+1; else hi = mid; }
  gstart[g] = lo;
}

// ---- per-node expert probs ----
__global__ void k_probs(const int* __restrict__ batch, const int* __restrict__ gstart,
                        const float* __restrict__ centers, float* __restrict__ probs){
  int n = blockIdx.x*blockDim.x + threadIdx.x;
  if(n >= NN) return;
  int b = batch[n];
  float c = (float)(gstart[b+1] - gstart[b]);
  float logn = logf(fmaxf(c, 1.f)) * (1.f/LOGN_SCALE);
  float s[NEXP]; float m = -1e30f;
  #pragma unroll
  for(int e=0;e<NEXP;e++){ float d = logn - centers[e]; s[e] = -d*d; m = fmaxf(m, s[e]); }
  float sum = 0.f;
  #pragma unroll
  for(int e=0;e<NEXP;e++){ s[e] = expf(s[e]-m); sum += s[e]; }
  float inv = 1.f/sum;
  #pragma unroll
  for(int e=0;e<NEXP;e++) probs[n*NEXP+e] = s[e]*inv;
}

// ---- encoder: h08 = fp8(relu(x @ Wenc + benc) * esc) ----
__global__ void k_enc(const float* __restrict__ x, const float* __restrict__ Wenc,
                      const float* __restrict__ benc, u8* __restrict__ h08, float esc){
  int t = blockIdx.x*blockDim.x + threadIdx.x;
  if(t >= NN*HID) return;
  int n = t >> 7, j = t & 127;
  float acc = benc[j];
  #pragma unroll
  for(int k=0;k<6;k++) acc += x[n*6+k]*Wenc[k*HID+j];
  h08[t] = f2fp8(fmaxf(acc, 0.f)*esc);
}

// ---- weights -> bf16, transposed+concatenated: WbfT[(e*3+l)][col j][k 0..255] ----
__global__ void k_wcvtT(const float* __restrict__ Wself, const float* __restrict__ Wnbr,
                        u16* __restrict__ WbfT){
  int t = blockIdx.x*blockDim.x + threadIdx.x;
  if(t >= 12*HID*256) return;
  int el = t / (HID*256);
  int r  = t % (HID*256);
  int j  = r >> 8;
  int k  = r & 255;
  float v = (k < HID) ? Wself[(size_t)el*HID*HID + (size_t)k*HID + j]
                      : Wnbr [(size_t)el*HID*HID + (size_t)(k-HID)*HID + j];
  WbfT[t] = f2bf(v);
}

// ==== bucketed CSR build ====
__global__ __launch_bounds__(256) void k_hist(const int* __restrict__ dst,
                                              int* __restrict__ hist){
  __shared__ int h[NBUK];
  for(int i=threadIdx.x; i<NBUK; i+=256) h[i] = 0;
  __syncthreads();
  int e0 = blockIdx.x*EPB, e1 = min(NE, e0 + EPB);
  for(int e = e0 + (int)threadIdx.x; e < e1; e += 256)
    atomicAdd(&h[dst[e]/NPB], 1);
  __syncthreads();
  for(int i=threadIdx.x; i<NBUK; i+=256) hist[blockIdx.x*NBUK + i] = h[i];
}

__global__ __launch_bounds__(1024) void k_hscan(const int* __restrict__ hist,
                                                int* __restrict__ hoff,
                                                int* __restrict__ bbase){
  __shared__ int sd[NBLK*NBUK];
  __shared__ int ps[1024];
  int t = threadIdx.x;
  for(int i=t; i<NBLK*NBUK; i+=1024){
    int bucket = i >> 7;
    int blk = i & (NBLK-1);
    sd[i] = hist[blk*NBUK + bucket];
  }
  __syncthreads();
  int base = t*32, sum = 0;
  #pragma unroll
  for(int i=0;i<32;i++){ int v = sd[base+i]; sd[base+i] = sum; sum += v; }
  ps[t] = sum;
  __syncthreads();
  for(int d=1; d<1024; d<<=1){
    int v = (t>=d) ? ps[t-d] : 0;
    __syncthreads();
    ps[t] += v;
    __syncthreads();
  }
  int add = (t>0) ? ps[t-1] : 0;
  for(int i=base; i<base+32; i++){
    int bucket = i >> 7, blk = i & (NBLK-1);
    int v = sd[i] + add;
    hoff[blk*NBUK + bucket] = v;
    if(blk == 0) bbase[bucket] = v;
  }
  if(t == 1023) bbase[NBUK] = NE;
}

__global__ __launch_bounds__(256) void k_scatter(const int* __restrict__ src,
                                                 const int* __restrict__ dst,
                                                 const int* __restrict__ hoff,
                                                 u32* __restrict__ packed){
  __shared__ u32 ent[EPB];
  __shared__ u32 outp[EPB];
  __shared__ u32 cnt[NBUK], exc[NBUK], cur[NBUK], gb[NBUK];
  int t = threadIdx.x;
  int e0 = blockIdx.x*EPB;
  int len = min(EPB, NE - e0);
  cnt[t] = 0;
  __syncthreads();
  for(int i=t; i<len; i+=256){
    int d = dst[e0+i];
    u32 b = (u32)(d/NPB);
    ent[i] = (u32)src[e0+i] | ((u32)(d - (int)b*NPB) << 16) | (b << 24);
    atomicAdd(&cnt[b], 1u);
  }
  __syncthreads();
  u32 c = cnt[t];
  exc[t] = c;
  __syncthreads();
  for(int d=1; d<256; d<<=1){
    u32 v = (t>=(u32)d) ? exc[t-d] : 0u;
    __syncthreads();
    exc[t] += v;
    __syncthreads();
  }
  u32 excl = exc[t] - c;
  cur[t] = excl;
  gb[t] = (u32)hoff[blockIdx.x*NBUK + t];
  __syncthreads();
  exc[t] = excl;
  __syncthreads();
  for(int i=t; i<len; i+=256){
    u32 v = ent[i];
    u32 p = atomicAdd(&cur[v>>24], 1u);
    outp[p] = v;
  }
  __syncthreads();
  for(int i=t; i<len; i+=256){
    u32 v = outp[i];
    u32 b = v >> 24;
    packed[gb[b] + ((u32)i - exc[b])] = v & 0x00ffffffu;
  }
}

__global__ __launch_bounds__(256) void k_build(const u32* __restrict__ packed,
                                               const int* __restrict__ bbase,
                                               int* __restrict__ offs,
                                               u16* __restrict__ srcs16){
  __shared__ u32 ent[MAXB];
  __shared__ u16 outb[MAXB];
  __shared__ u32 cnt[256], exc[256], cur[256];
  int b = blockIdx.x, t = threadIdx.x;
  int e0 = bbase[b], e1 = bbase[b+1];
  int len = e1 - e0, cap = min(len, MAXB);
  for(int i=t; i<cap; i+=256) ent[i] = packed[e0+i];
  cnt[t] = 0;
  __syncthreads();
  for(int i=t; i<len; i+=256){
    u32 v = (i < MAXB) ? ent[i] : packed[e0+i];
    atomicAdd(&cnt[(v>>16)&0xffu], 1u);
  }
  __syncthreads();
  u32 c = cnt[t];
  exc[t] = c;
  __syncthreads();
  for(int d=1; d<256; d<<=1){
    u32 v = (t>=(u32)d) ? exc[t-d] : 0u;
    __syncthreads();
    exc[t] += v;
    __syncthreads();
  }
  u32 excl = exc[t] - c;
  int node = b*NPB + t;
  if(t < NPB && node < NN) offs[node] = e0 + (int)excl;
  cur[t] = excl;
  if(b == NBUK-1 && t == 0) offs[NN] = NE;
  __syncthreads();
  for(int i=t; i<len; i+=256){
    u32 v = (i < MAXB) ? ent[i] : packed[e0+i];
    u32 p = atomicAdd(&cur[(v>>16)&0xffu], 1u);
    u16 sv = (u16)(v & 0xffffu);
    if(p < (u32)MAXB) outb[p] = sv;
    else srcs16[e0+p] = sv;
  }
  __syncthreads();
  for(int i=t; i<cap; i+=256) srcs16[e0+i] = outb[i];
}

// ==== fused layer: gather (fp8 table -> LDS bf16 agg) + dual GEMM (MFMA) ====
// TW = input table row bytes (128 for layer 0, 512 otherwise).
// Non-LAST: wave = expert; writes fp8 table rows of 512 B.
// LAST: wave = 32-col slice; combines 4 experts with probs in-register -> fp32 out.
template<int TW, bool RELU, bool LAST>
__global__ __launch_bounds__(256) void k_fused(
    const u8* __restrict__ tin, const int* __restrict__ offs,
    const u16* __restrict__ srcs, const u16* __restrict__ WbfT,
    const float* __restrict__ bconv, int layer,
    const float* __restrict__ probs,
    u8* __restrict__ tout, float* __restrict__ outp,
    float bias_fold, float store_fold)
{
  constexpr int BPL = TW/64;
  __shared__ u16 G[32*TW];   // agg rows, bf16, table units, XOR-swizzled
  int wave = threadIdx.x>>6, lane = threadIdx.x&63;
  int l16 = lane&15, lq = lane>>4;
  int n0 = blockIdx.x*32;

  // ---- gather phase: 8 nodes per wave ----
  const u8* hbase = tin + lane*BPL;
  for(int i=0;i<8;i++){
    int row = wave*8 + i;
    int node = n0 + row;
    float acc[BPL];
    #pragma unroll
    for(int b=0;b<BPL;b++) acc[b]=0.f;
    if(node < NN){
      int beg = offs[node], end = offs[node+1];
      for(int eb=beg; eb<end; eb+=64){
        int idx = eb + lane;
        int s = (idx < end) ? (int)srcs[idx] : 0;
        int cnt = min(64, end-eb);
        int j = 0;
        if(BPL == 8){
          for(; j+8<=cnt; j+=8){
            uint2 v[8];
            #pragma unroll
            for(int u=0;u<8;u++){
              int sj = __shfl(s, j+u, 64);
              v[u] = *(const uint2*)(hbase + (size_t)sj*TW);
            }
            #pragma unroll
            for(int u=0;u<8;u++){
              f32x2 f0 = __builtin_amdgcn_cvt_pk_f32_fp8(v[u].x, false);
              f32x2 f1 = __builtin_amdgcn_cvt_pk_f32_fp8(v[u].x, true);
              f32x2 f2 = __builtin_amdgcn_cvt_pk_f32_fp8(v[u].y, false);
              f32x2 f3 = __builtin_amdgcn_cvt_pk_f32_fp8(v[u].y, true);
              acc[0]+=f0.x; acc[1]+=f0.y; acc[2]+=f1.x; acc[3]+=f1.y;
              acc[4]+=f2.x; acc[5]+=f2.y; acc[6]+=f3.x; acc[7]+=f3.y;
            }
          }
          for(; j<cnt; j++){
            int sj = __shfl(s, j, 64);
            uint2 v = *(const uint2*)(hbase + (size_t)sj*TW);
            f32x2 f0 = __builtin_amdgcn_cvt_pk_f32_fp8(v.x, false);
            f32x2 f1 = __builtin_amdgcn_cvt_pk_f32_fp8(v.x, true);
            f32x2 f2 = __builtin_amdgcn_cvt_pk_f32_fp8(v.y, false);
            f32x2 f3 = __builtin_amdgcn_cvt_pk_f32_fp8(v.y, true);
            acc[0]+=f0.x; acc[1]+=f0.y; acc[2]+=f1.x; acc[3]+=f1.y;
            acc[4]+=f2.x; acc[5]+=f2.y; acc[6]+=f3.x; acc[7]+=f3.y;
          }
        } else {
          for(; j+8<=cnt; j+=8){
            u32 v[8];
            #pragma unroll
            for(int u=0;u<8;u++){
              int sj = __shfl(s, j+u, 64);
              v[u] = *(const u16*)(hbase + (size_t)sj*TW);
            }
            #pragma unroll
            for(int u=0;u<8;u++){
              f32x2 f0 = __builtin_amdgcn_cvt_pk_f32_fp8(v[u], false);
              acc[0]+=f0.x; acc[1]+=f0.y;
            }
          }
          for(; j<cnt; j++){
            int sj = __shfl(s, j, 64);
            u32 v = *(const u16*)(hbase + (size_t)sj*TW);
            f32x2 f0 = __builtin_amdgcn_cvt_pk_f32_fp8(v, false);
            acc[0]+=f0.x; acc[1]+=f0.y;
          }
        }
      }  // eb loop
    }    // if(node < NN)
    // write agg row to LDS (bf16, table units), swizzled
    u32 boff = (u32)(lane*BPL*2) ^ (u32)((row&7)<<4);
    u16* gp = (u16*)((char*)G + (size_t)row*(TW*2) + boff);
    if(BPL == 8){
      short8b tv;
      #pragma unroll
      for(int b=0;b<8;b++) tv[b] = (short)f2bf(acc[b]);
      *(short8b*)gp = tv;
    } else {
      gp[0] = f2bf(acc[0]); gp[1] = f2bf(acc[1]);
    }
  }
  __syncthreads();

  // ---- MFMA phase ----
  if(!LAST){
    int e = wave;
    const u16* WT = WbfT + (size_t)((e*3+layer)*HID)*256;
    const int eoff = (TW==512) ? e*128 : 0;
    // A-frags hoisted: ks<4 self (global fp8 -> bf16), ks>=4 agg (LDS)
    short8b Af[2][8];
    #pragma unroll
    for(int rt=0; rt<2; rt++){
      int n = n0 + rt*16 + l16; if(n > NN-1) n = NN-1;
      const u8* srow = tin + (size_t)n*TW;
      #pragma unroll
      for(int ks=0; ks<4; ks++)
        Af[rt][ks] = fp8x8_to_bf16(*(const uint2*)(srow + eoff + ks*32 + lq*8));
      int row = rt*16 + l16;
      #pragma unroll
      for(int ks=4; ks<8; ks++){
        u32 boff = (u32)((eoff + (ks-4)*32 + lq*8)*2) ^ (u32)((row&7)<<4);
        Af[rt][ks] = *(const short8b*)((char*)G + (size_t)row*(TW*2) + boff);
      }
    }
    const float* bias = bconv + (e*3+layer)*HID;
    #pragma unroll 1
    for(int ct=0; ct<8; ct++){
      f32x4 binit = *(const f32x4*)(bias + ct*16 + lq*4);
      f32x4 acc0, acc1;
      #pragma unroll
      for(int r=0;r<4;r++){ acc0[r] = binit[r]*bias_fold; acc1[r] = acc0[r]; }
      const u16* wp = WT + (size_t)(ct*16 + l16)*256 + lq*8;
      #pragma unroll
      for(int ks=0; ks<8; ks++){
        short8b Bf = *(const short8b*)(wp + ks*32);
        acc0 = __builtin_amdgcn_mfma_f32_16x16x32_bf16(Bf, Af[0][ks], acc0, 0,0,0);
        acc1 = __builtin_amdgcn_mfma_f32_16x16x32_bf16(Bf, Af[1][ks], acc1, 0,0,0);
      }
      // D: col(lane&15)=node, row(lq*4+r)=output col -> 4 consecutive fp8 bytes
      #pragma unroll
      for(int rt=0; rt<2; rt++){
        int n = n0 + rt*16 + l16;
        if(n < NN){
          f32x4 a = rt ? acc1 : acc0;
          float v0,v1,v2,v3;
          if(RELU){
            v0=fmaxf(a[0],0.f)*store_fold; v1=fmaxf(a[1],0.f)*store_fold;
            v2=fmaxf(a[2],0.f)*store_fold; v3=fmaxf(a[3],0.f)*store_fold;
          } else {
            v0=a[0]*store_fold; v1=a[1]*store_fold; v2=a[2]*store_fold; v3=a[3]*store_fold;
          }
          u32 wv = __builtin_amdgcn_cvt_pk_fp8_f32(v0, v1, 0, false);
          wv = __builtin_amdgcn_cvt_pk_fp8_f32(v2, v3, wv, true);
          *(u32*)(tout + (size_t)n*512 + e*128 + ct*16 + lq*4) = wv;
        }
      }
    }
  } else {
    // LAST: wave owns cols [wave*32, wave*32+32); loop experts, combine with probs
    f32x4 tot[2][2];
    #pragma unroll
    for(int rt=0;rt<2;rt++){
      #pragma unroll
      for(int ct=0;ct<2;ct++){
        #pragma unroll
        for(int r=0;r<4;r++) tot[rt][ct][r] = 0.f;
      }
    }
    float pv[2][4];
    #pragma unroll
    for(int rt=0;rt<2;rt++){
      int n = n0 + rt*16 + l16; if(n > NN-1) n = NN-1;
      #pragma unroll
      for(int e=0;e<4;e++) pv[rt][e] = probs[n*NEXP + e];
    }
    #pragma unroll 1
    for(int e=0;e<4;e++){
      const u16* WT = WbfT + (size_t)((e*3+layer)*HID)*256;
      const int eoff = e*128;
      short8b Af[2][8];
      #pragma unroll
      for(int rt=0; rt<2; rt++){
        int n = n0 + rt*16 + l16; if(n > NN-1) n = NN-1;
        const u8* srow = tin + (size_t)n*TW;
        #pragma unroll
        for(int ks=0; ks<4; ks++)
          Af[rt][ks] = fp8x8_to_bf16(*(const uint2*)(srow + eoff + ks*32 + lq*8));
        int row = rt*16 + l16;
        #pragma unroll
        for(int ks=4; ks<8; ks++){
          u32 boff = (u32)((eoff + (ks-4)*32 + lq*8)*2) ^ (u32)((row&7)<<4);
          Af[rt][ks] = *(const short8b*)((char*)G + (size_t)row*(TW*2) + boff);
        }
      }
      const float* bias = bconv + (e*3+layer)*HID;
      #pragma unroll
      for(int ct=0; ct<2; ct++){
        int cb = wave*32 + ct*16;
        f32x4 binit = *(const f32x4*)(bias + cb + lq*4);
        f32x4 acc0, acc1;
        #pragma unroll
        for(int r=0;r<4;r++){ acc0[r] = binit[r]*bias_fold; acc1[r] = acc0[r]; }
        const u16* wp = WT + (size_t)(cb + l16)*256 + lq*8;
        #pragma unroll
        for(int ks=0; ks<8; ks++){
          short8b Bf = *(const short8b*)(wp + ks*32);
          acc0 = __builtin_amdgcn_mfma_f32_16x16x32_bf16(Bf, Af[0][ks], acc0, 0,0,0);
          acc1 = __builtin_amdgcn_mfma_f32_16x16x32_bf16(Bf, Af[1][ks], acc1, 0,0,0);
        }
        float s0 = pv[0][e]*store_fold, s1 = pv[1][e]*store_fold;
        #pragma unroll
        for(int r=0;r<4;r++){
          tot[0][ct][r] += s0*acc0[r];
          tot[1][ct][r] += s1*acc1[r];
        }
      }
    }
    #pragma unroll
    for(int rt=0; rt<2; rt++){
      int n = n0 + rt*16 + l16;
      if(n < NN){
        #pragma unroll
        for(int ct=0; ct<2; ct++)
          *(f32x4*)(outp + (size_t)n*HID + wave*32 + ct*16 + lq*4) = tot[rt][ct];
      }
    }
  }
}

extern "C" void kernel_launch(void* const* d_in, const int* in_sizes, int n_in,
                              void* d_out, int out_size, void* d_ws, size_t ws_size,
                              hipStream_t stream){
  const float* x      = (const float*)d_in[0];
  const int*   eidx   = (const int*)d_in[1];
  const int*   batch  = (const int*)d_in[2];
  const float* Wenc   = (const float*)d_in[3];
  const float* benc   = (const float*)d_in[4];
  const float* Wself  = (const float*)d_in[5];
  const float* Wnbr   = (const float*)d_in[6];
  const float* bconv  = (const float*)d_in[7];
  const float* centers= (const float*)d_in[8];
  float* out = (float*)d_out;
  const int* src = eidx;
  const int* dst = eidx + NE;

  char* w = (char*)d_ws;
  size_t off = 0;
  auto alloc = [&](size_t b)->char*{ char* p = w + off; off = (off + b + 255) & ~(size_t)255; return p; };

  u8*  h08   = (u8*)alloc((size_t)NN*HID);            // 6.4 MB
  u8*  hA8   = (u8*)alloc((size_t)NN*NEXP*HID);       // 25.6 MB
  u8*  hB8   = (u8*)alloc((size_t)NN*NEXP*HID);       // 25.6 MB
  u16* WbfT  = (u16*)alloc((size_t)12*HID*256*2);     // 1.57 MB
  float* probs = (float*)alloc((size_t)NN*NEXP*4);
  int* gstart = (int*)alloc(256);
  int* offs  = (int*)alloc((size_t)(NN+1)*4);
  u32* packed= (u32*)alloc((size_t)NE*4);
  u16* srcs16= (u16*)alloc((size_t)NE*2);
  int* hist  = (int*)alloc((size_t)NBLK*NBUK*4);
  int* hoff  = (int*)alloc((size_t)NBLK*NBUK*4);
  int* bbase = (int*)alloc((size_t)(NBUK+1)*4);
  if(off > ws_size) return;

  k_bounds<<<1, 32, 0, stream>>>(batch, gstart);
  k_probs<<<(NN+255)/256, 256, 0, stream>>>(batch, gstart, centers, probs);
  k_enc<<<(NN*HID+255)/256, 256, 0, stream>>>(x, Wenc, benc, h08, 0.5f);
  k_wcvtT<<<(12*HID*256+255)/256, 256, 0, stream>>>(Wself, Wnbr, WbfT);

  k_hist<<<NBLK, 256, 0, stream>>>(dst, hist);
  k_hscan<<<1, 1024, 0, stream>>>(hist, hoff, bbase);
  k_scatter<<<NBLK, 256, 0, stream>>>(src, dst, hoff, packed);
  k_build<<<NBUK, 256, 0, stream>>>(packed, bbase, offs, srcs16);

  int nblocks = (NN + 31)/32;  // 1563
  // scales: esc0=0.5, escA=1/16, escB=1/32
  // layer 0: bias_fold=0.5, store_fold = 2 * (1/16) = 0.125
  k_fused<128,true,false><<<nblocks, 256, 0, stream>>>(
      h08, offs, srcs16, WbfT, bconv, 0, nullptr, hA8, nullptr, 0.5f, 0.125f);
  // layer 1: bias_fold=1/16, store_fold = 16 * (1/32) = 0.5
  k_fused<512,true,false><<<nblocks, 256, 0, stream>>>(
      hA8, offs, srcs16, WbfT, bconv, 1, nullptr, hB8, nullptr, 0.0625f, 0.5f);
  // layer 2 (LAST): bias_fold=1/32, store_fold = inv_esc = 32
  k_fused<512,false,true><<<nblocks, 256, 0, stream>>>(
      hB8, offs, srcs16, WbfT, bconv, 2, probs, nullptr, out, 0.03125f, 32.0f);
}